// Round 4
// baseline (452.354 us; speedup 1.0000x reference)
//
#include <hip/hip_runtime.h>
#include <hip/hip_bf16.h>
#include <stdint.h>

typedef __attribute__((ext_vector_type(8))) short short8;
typedef __attribute__((ext_vector_type(4))) float floatx4;

#define NB 4
#define NN 8192
#define NC 768
#define NH 12
#define ND 64
#define LDQKV 2304

// ---------- helpers ----------
__device__ __forceinline__ float bf2f(ushort u) {
    union { float f; uint32_t i; } x; x.i = ((uint32_t)u) << 16; return x.f;
}
__device__ __forceinline__ ushort f2bf(float f) {
    union { float f; uint32_t i; } x; x.f = f;
    uint32_t r = x.i + 0x7fff + ((x.i >> 16) & 1);
    return (ushort)(r >> 16);
}
// async global->LDS, 16B per lane: lane i lands at ldsbase + 16*i (wave-uniform base).
typedef const __attribute__((address_space(1))) uint32_t* gas1_t;
typedef __attribute__((address_space(3))) uint32_t* las3_t;
__device__ __forceinline__ void gl_lds16(const void* g, const void* l) {
    __builtin_amdgcn_global_load_lds((gas1_t)(uintptr_t)g,
                                     (las3_t)(uint32_t)(uintptr_t)l, 16, 0, 0);
}

// ---------- fp32 -> bf16 bulk convert (8 elems/thread, 16B stores) ----------
__global__ __launch_bounds__(256) void cvt_bf16(const float* __restrict__ src,
                                                ushort* __restrict__ dst, int n) {
    const int i = (blockIdx.x * 256 + threadIdx.x) * 8;
    if (i >= n) return;
    const float4 a = *(const float4*)(src + i);
    const float4 b = *(const float4*)(src + i + 4);
    short8 v;
    v[0] = (short)f2bf(a.x); v[1] = (short)f2bf(a.y);
    v[2] = (short)f2bf(a.z); v[3] = (short)f2bf(a.w);
    v[4] = (short)f2bf(b.x); v[5] = (short)f2bf(b.y);
    v[6] = (short)f2bf(b.z); v[7] = (short)f2bf(b.w);
    *(short8*)(dst + i) = v;
}

// ============ 256x256 8-phase GEMM (QKV): C = act(A @ Bw^T) ============
// 512 threads = 8 waves (2M x 4N); per-wave 128x64 out; BK=64; 128 KiB LDS.
// Two-barrier phase lockstep (R1 structure). v3: lead-2 prefetch — iter j
// stages B(j+2) at ph2/ph3 and A(j+2) at ph3 (region lifetimes: A(j) last
// read ph2, B(j) last read ph1 -> same-parity buffer is free). Steady-state
// vmcnt(8) at ph3 waits loads issued 4-6 phases earlier (was 3).
// LDS XOR-swizzle on stage-source + reads (T2; conflicts measured 0).

// stage one 128x64 half-tile (2 x gl_lds16 per thread), source-side swizzle
__device__ __forceinline__ void stage_half(const ushort* __restrict__ src, int row0,
                                           int k0, int K, ushort* dst, int t, int w) {
    const int rsub = t >> 3;                       // 0..63
    const int ch = (t & 7) ^ (rsub & 7);           // inverse of read-side XOR
    const ushort* g0 = src + (size_t)(row0 + rsub) * K + k0 + ch * 8;
    gl_lds16(g0,                 dst + w * 512);
    gl_lds16(g0 + (size_t)64 * K, dst + 4096 + w * 512);
}

#define PHASE_SYNC() do {                                        \
    __builtin_amdgcn_s_barrier();                                \
    asm volatile("s_waitcnt lgkmcnt(0)" ::: "memory");           \
    __builtin_amdgcn_sched_barrier(0);                           \
} while (0)

template<int LDC, bool ELU, bool BIAS, typename OutT>
__global__ __launch_bounds__(512) void gemm256(const ushort* __restrict__ A,
                                               const ushort* __restrict__ Bw,
                                               const float* __restrict__ bias,
                                               OutT* __restrict__ Cout, int K) {
    __shared__ __align__(16) ushort SL[2][4][8192];   // [buf][region][128*64]
    const int t = threadIdx.x, w = t >> 6, lane = t & 63;
    const int l16 = lane & 15, quad = lane >> 4;
    const int wm = w >> 2, wn = w & 3;
    const int bro = (wn & 1) * 64;                    // row offset inside B region

    const int gx = gridDim.x;
    const int nwg = gx * gridDim.y;
    int bid = blockIdx.y * gx + blockIdx.x;
    bid = (bid & 7) * (nwg >> 3) + (bid >> 3);        // XCD swizzle (nwg % 8 == 0)
    const int m0 = (bid / gx) * 256;
    const int n0 = (bid % gx) * 256;
    const int NT = K >> 6;                            // K-tiles of 64 (NT >= 3)

    floatx4 acc[8][4] = {};
    short8 af[4][2], b01[2][2], b23[2][2];

    // prologue: tiles 0 and 1 fully staged (16 gl_lds/thread), wait tile 0
    stage_half(Bw, n0,       0,  K, &SL[0][0][0], t, w);
    stage_half(Bw, n0 + 128, 0,  K, &SL[0][1][0], t, w);
    stage_half(A,  m0,       0,  K, &SL[0][2][0], t, w);
    stage_half(A,  m0 + 128, 0,  K, &SL[0][3][0], t, w);
    stage_half(Bw, n0,       64, K, &SL[1][0][0], t, w);
    stage_half(Bw, n0 + 128, 64, K, &SL[1][1][0], t, w);
    stage_half(A,  m0,       64, K, &SL[1][2][0], t, w);
    stage_half(A,  m0 + 128, 64, K, &SL[1][3][0], t, w);
    asm volatile("s_waitcnt vmcnt(8)" ::: "memory");  // tile 0 resident, tile 1 in flight
    __builtin_amdgcn_s_barrier();

    for (int j = 0; j < NT; j++) {
        const int buf = j & 1;
        const ushort* As = &SL[buf][2 + wm][0];
        const ushort* Bs = &SL[buf][wn >> 1][0];

        // ---- phase 0: read A(m_lo) + B(n0,n1) [12 ds_reads]
        #pragma unroll
        for (int mi = 0; mi < 4; mi++) {
            const int row = mi * 16 + l16;
            const int sw = (row & 7) << 3;
            const int base = row * 64 + quad * 8;
            af[mi][0] = *(const short8*)&As[base ^ sw];
            af[mi][1] = *(const short8*)&As[(base + 32) ^ sw];
        }
        #pragma unroll
        for (int ni = 0; ni < 2; ni++) {
            const int row = bro + ni * 16 + l16;
            const int sw = (row & 7) << 3;
            const int base = row * 64 + quad * 8;
            b01[ni][0] = *(const short8*)&Bs[base ^ sw];
            b01[ni][1] = *(const short8*)&Bs[(base + 32) ^ sw];
        }
        asm volatile("s_waitcnt lgkmcnt(8)" ::: "memory");  // template hint: 12 reads issued
        PHASE_SYNC();
        __builtin_amdgcn_s_setprio(1);
        #pragma unroll
        for (int mi = 0; mi < 4; mi++)
            #pragma unroll
            for (int ni = 0; ni < 2; ni++) {
                acc[mi][ni] = __builtin_amdgcn_mfma_f32_16x16x32_bf16(af[mi][0], b01[ni][0], acc[mi][ni], 0, 0, 0);
                acc[mi][ni] = __builtin_amdgcn_mfma_f32_16x16x32_bf16(af[mi][1], b01[ni][1], acc[mi][ni], 0, 0, 0);
            }
        __builtin_amdgcn_s_setprio(0);
        __builtin_amdgcn_s_barrier();

        // ---- phase 1: read B(n2,n3); MFMA m_lo x n23
        #pragma unroll
        for (int ni = 0; ni < 2; ni++) {
            const int row = bro + (2 + ni) * 16 + l16;
            const int sw = (row & 7) << 3;
            const int base = row * 64 + quad * 8;
            b23[ni][0] = *(const short8*)&Bs[base ^ sw];
            b23[ni][1] = *(const short8*)&Bs[(base + 32) ^ sw];
        }
        PHASE_SYNC();
        __builtin_amdgcn_s_setprio(1);
        #pragma unroll
        for (int mi = 0; mi < 4; mi++)
            #pragma unroll
            for (int ni = 0; ni < 2; ni++) {
                acc[mi][2 + ni] = __builtin_amdgcn_mfma_f32_16x16x32_bf16(af[mi][0], b23[ni][0], acc[mi][2 + ni], 0, 0, 0);
                acc[mi][2 + ni] = __builtin_amdgcn_mfma_f32_16x16x32_bf16(af[mi][1], b23[ni][1], acc[mi][2 + ni], 0, 0, 0);
            }
        __builtin_amdgcn_s_setprio(0);
        __builtin_amdgcn_s_barrier();

        // ---- phase 2: read A(m_hi); stage B-lo(j+2) (B(j)-lo reads done ph0); MFMA m_hi x n01
        #pragma unroll
        for (int mi = 0; mi < 4; mi++) {
            const int row = (4 + mi) * 16 + l16;
            const int sw = (row & 7) << 3;
            const int base = row * 64 + quad * 8;
            af[mi][0] = *(const short8*)&As[base ^ sw];
            af[mi][1] = *(const short8*)&As[(base + 32) ^ sw];
        }
        if (j + 2 < NT) stage_half(Bw, n0, (j + 2) * 64, K, &SL[buf][0][0], t, w);
        PHASE_SYNC();
        __builtin_amdgcn_s_setprio(1);
        #pragma unroll
        for (int mi = 0; mi < 4; mi++)
            #pragma unroll
            for (int ni = 0; ni < 2; ni++) {
                acc[4 + mi][ni] = __builtin_amdgcn_mfma_f32_16x16x32_bf16(af[mi][0], b01[ni][0], acc[4 + mi][ni], 0, 0, 0);
                acc[4 + mi][ni] = __builtin_amdgcn_mfma_f32_16x16x32_bf16(af[mi][1], b01[ni][1], acc[4 + mi][ni], 0, 0, 0);
            }
        __builtin_amdgcn_s_setprio(0);
        __builtin_amdgcn_s_barrier();

        // ---- phase 3: stage B-hi(j+2) + A-lo/hi(j+2) (A(j) reads done ph2);
        //      MFMA m_hi x n23; steady-state vmcnt(8)
        if (j + 2 < NT) {
            stage_half(Bw, n0 + 128, (j + 2) * 64, K, &SL[buf][1][0], t, w);
            stage_half(A,  m0,       (j + 2) * 64, K, &SL[buf][2][0], t, w);
            stage_half(A,  m0 + 128, (j + 2) * 64, K, &SL[buf][3][0], t, w);
        }
        __builtin_amdgcn_s_barrier();
        __builtin_amdgcn_s_setprio(1);
        #pragma unroll
        for (int mi = 0; mi < 4; mi++)
            #pragma unroll
            for (int ni = 0; ni < 2; ni++) {
                acc[4 + mi][2 + ni] = __builtin_amdgcn_mfma_f32_16x16x32_bf16(af[mi][0], b23[ni][0], acc[4 + mi][2 + ni], 0, 0, 0);
                acc[4 + mi][2 + ni] = __builtin_amdgcn_mfma_f32_16x16x32_bf16(af[mi][1], b23[ni][1], acc[4 + mi][2 + ni], 0, 0, 0);
            }
        __builtin_amdgcn_s_setprio(0);
        // tile j+1 (issued last iter) must be resident; leave tile j+2's 8 in flight
        if (j < NT - 2) asm volatile("s_waitcnt vmcnt(8)" ::: "memory");
        else            asm volatile("s_waitcnt vmcnt(0)" ::: "memory");
        __builtin_amdgcn_s_barrier();
    }

    // ---- epilogue
    #pragma unroll
    for (int mi = 0; mi < 8; mi++) {
        const int row = m0 + wm * 128 + mi * 16 + quad * 4;
        #pragma unroll
        for (int n = 0; n < 4; n++) {
            const int col = n0 + wn * 64 + n * 16 + l16;
            float bval = 0.f;
            if (BIAS) bval = bias[col];
            #pragma unroll
            for (int r = 0; r < 4; r++) {
                float v = acc[mi][n][r];
                if (ELU) { if (col < 2 * NC) v = (v > 0.f) ? v + 1.f : __expf(v); }
                if (BIAS) v += bval;
                if (sizeof(OutT) == 2) Cout[(size_t)(row + r) * LDC + col] = (OutT)f2bf(v);
                else                   Cout[(size_t)(row + r) * LDC + col] = (OutT)v;
            }
        }
    }
}

// ============ 128x128 2-phase GEMM (proj): better tail at small N ============
// 256 threads (4 waves, 2x2), 4x4 16x16x32 MFMA per wave, BK=32, 16 KiB LDS
// -> 2 blocks/CU; grid 6x256 = 1536 blocks = 3 exact generations.
template<int LDC, bool ELU, bool BIAS, typename OutT>
__global__ __launch_bounds__(256) void gemm_bt(const ushort* __restrict__ A,
                                               const ushort* __restrict__ Bw,
                                               const float* __restrict__ bias,
                                               OutT* __restrict__ Cout, int K) {
    __shared__ ushort As[128 * 32];
    __shared__ ushort Bs[128 * 32];
    const int t = threadIdx.x;
    const int w = t >> 6, lane = t & 63, l16 = lane & 15, quad = lane >> 4;
    const int wm = w & 1, wn = w >> 1;
    const int m0 = blockIdx.y * 128, n0 = blockIdx.x * 128;

    floatx4 acc[4][4] = {};

    const int rowA = t >> 2, chA = t & 3;            // 64 rows x 4 chunks of 16B
    const ushort* gA = A  + (size_t)(m0 + rowA) * K + chA * 8;
    const ushort* gB = Bw + (size_t)(n0 + rowA) * K + chA * 8;

    for (int k0 = 0; k0 < K; k0 += 32) {
        gl_lds16(gA + k0,                As + w * 512);
        gl_lds16(gA + k0 + 64 * K,       As + 2048 + w * 512);
        gl_lds16(gB + k0,                Bs + w * 512);
        gl_lds16(gB + k0 + 64 * K,       Bs + 2048 + w * 512);
        __syncthreads();
        short8 af[4], bfr[4];
        #pragma unroll
        for (int i = 0; i < 4; i++)
            af[i] = *(const short8*)&As[(wm * 64 + i * 16 + l16) * 32 + quad * 8];
        #pragma unroll
        for (int j = 0; j < 4; j++)
            bfr[j] = *(const short8*)&Bs[(wn * 64 + j * 16 + l16) * 32 + quad * 8];
        #pragma unroll
        for (int i = 0; i < 4; i++)
            #pragma unroll
            for (int j = 0; j < 4; j++)
                acc[i][j] = __builtin_amdgcn_mfma_f32_16x16x32_bf16(af[i], bfr[j], acc[i][j], 0, 0, 0);
        __syncthreads();
    }

    #pragma unroll
    for (int i = 0; i < 4; i++) {
        const int row = m0 + wm * 64 + i * 16 + quad * 4;
        #pragma unroll
        for (int j = 0; j < 4; j++) {
            const int col = n0 + wn * 64 + j * 16 + l16;
            float bval = 0.f;
            if (BIAS) bval = bias[col];
            #pragma unroll
            for (int r = 0; r < 4; r++) {
                float v = acc[i][j][r];
                if (ELU) { if (col < 2 * NC) v = (v > 0.f) ? v + 1.f : __expf(v); }
                if (BIAS) v += bval;
                if (sizeof(OutT) == 2) Cout[(size_t)(row + r) * LDC + col] = (OutT)f2bf(v);
                else                   Cout[(size_t)(row + r) * LDC + col] = (OutT)v;
            }
        }
    }
}

// ---------- kv_part[c][bh][d][e] = sum_n k[n,d] v[n,e] over n-chunk c; also ksum ----------
// atomics-free; ksum via MFMA vs all-ones. v3: double-buffered staging with
// raw s_barrier + counted vmcnt (old __syncthreads drained vmcnt(0) -> 8
// exposed HBM round-trips per block).
__global__ __launch_bounds__(256) void kv_ksum(const ushort* __restrict__ qkv,
                                               float* __restrict__ kv_part,
                                               float* __restrict__ ks_part) {
    __shared__ ushort kvsh[2][2][128 * 64];   // [buf][k/v][...]; reused as f32 scratch
    __shared__ float  ksred[4][64];
    const int bh = blockIdx.y, b = bh / NH, h = bh % NH;
    const int t = threadIdx.x, w = t >> 6, lane = t & 63, l16 = lane & 15, quad = lane >> 4;
    const int n0 = blockIdx.x * 1024;
    const ushort* kbase = qkv + (size_t)(b * NN) * LDQKV + NC     + h * ND;
    const ushort* vbase = qkv + (size_t)(b * NN) * LDQKV + 2 * NC + h * ND;

    floatx4 acc[4][4] = {};
    floatx4 aks[4] = {};
    short8 bones;
    #pragma unroll
    for (int j = 0; j < 8; j++) bones[j] = (short)0x3F80;   // bf16 1.0
    const int rowT = t >> 3, ch = t & 7;   // 32 rows x 8 chunks of 16B per issue

    // stage chunk s into buffer s&1 (8 gl_lds/thread)
    #define KV_STAGE(s) do {                                                  \
        const int nb_ = n0 + (s) * 128;                                       \
        _Pragma("unroll")                                                     \
        for (int i_ = 0; i_ < 4; i_++) {                                      \
            const size_t r_ = (size_t)(nb_ + i_ * 32 + rowT) * LDQKV + ch * 8;\
            gl_lds16(kbase + r_, &kvsh[(s) & 1][0][0] + i_ * 2048 + w * 512); \
            gl_lds16(vbase + r_, &kvsh[(s) & 1][1][0] + i_ * 2048 + w * 512); \
        }                                                                     \
    } while (0)

    KV_STAGE(0);
    for (int s = 0; s < 8; s++) {
        if (s < 7) KV_STAGE(s + 1);
        if (s < 7) asm volatile("s_waitcnt vmcnt(8)" ::: "memory");
        else       asm volatile("s_waitcnt vmcnt(0)" ::: "memory");
        __builtin_amdgcn_s_barrier();
        const ushort* klds = &kvsh[s & 1][0][0];
        const ushort* vlds = &kvsh[s & 1][1][0];
        short8 af[4], bfr[4];
        #pragma unroll
        for (int dt = 0; dt < 4; dt++) {
            short8 v;
            #pragma unroll
            for (int j = 0; j < 8; j++)
                v[j] = (short)klds[(w * 32 + quad * 8 + j) * 64 + dt * 16 + l16];
            af[dt] = v;
        }
        #pragma unroll
        for (int et = 0; et < 4; et++) {
            short8 v;
            #pragma unroll
            for (int j = 0; j < 8; j++)
                v[j] = (short)vlds[(w * 32 + quad * 8 + j) * 64 + et * 16 + l16];
            bfr[et] = v;
        }
        #pragma unroll
        for (int dt = 0; dt < 4; dt++) {
            #pragma unroll
            for (int et = 0; et < 4; et++)
                acc[dt][et] = __builtin_amdgcn_mfma_f32_16x16x32_bf16(af[dt], bfr[et], acc[dt][et], 0, 0, 0);
            aks[dt] = __builtin_amdgcn_mfma_f32_16x16x32_bf16(af[dt], bones, aks[dt], 0, 0, 0);
        }
        __builtin_amdgcn_s_barrier();   // buf s&1 reads done before stage(s+2) next iter
    }
    #undef KV_STAGE

    // ksum wave partials: lane l16==0 holds ksum[dt*16+quad*4+r] (dup over cols)
    if (l16 == 0) {
        #pragma unroll
        for (int dt = 0; dt < 4; dt++)
            #pragma unroll
            for (int r = 0; r < 4; r++)
                ksred[w][dt * 16 + quad * 4 + r] = aks[dt][r];
    }

    // kv barrier-tree reduce across the 4 waves via LDS scratch (no atomics)
    float* scratch = (float*)kvsh;         // 8192 floats needed, 64 KB available
    if (w >= 2) {
        float* dst = scratch + (w - 2) * 4096;
        #pragma unroll
        for (int dt = 0; dt < 4; dt++)
            #pragma unroll
            for (int et = 0; et < 4; et++)
                #pragma unroll
                for (int r = 0; r < 4; r++)
                    dst[(dt * 16 + quad * 4 + r) * 64 + et * 16 + l16] = acc[dt][et][r];
    }
    __syncthreads();
    if (w < 2) {
        const float* srcp = scratch + w * 4096;
        #pragma unroll
        for (int dt = 0; dt < 4; dt++)
            #pragma unroll
            for (int et = 0; et < 4; et++)
                #pragma unroll
                for (int r = 0; r < 4; r++)
                    acc[dt][et][r] += srcp[(dt * 16 + quad * 4 + r) * 64 + et * 16 + l16];
    }
    __syncthreads();
    if (w == 1) {
        #pragma unroll
        for (int dt = 0; dt < 4; dt++)
            #pragma unroll
            for (int et = 0; et < 4; et++)
                #pragma unroll
                for (int r = 0; r < 4; r++)
                    scratch[(dt * 16 + quad * 4 + r) * 64 + et * 16 + l16] = acc[dt][et][r];
    }
    __syncthreads();
    if (w == 0) {
        float* outp = kv_part + ((size_t)blockIdx.x * 48 + bh) * 4096;
        #pragma unroll
        for (int dt = 0; dt < 4; dt++)
            #pragma unroll
            for (int et = 0; et < 4; et++)
                #pragma unroll
                for (int r = 0; r < 4; r++) {
                    const int idx = (dt * 16 + quad * 4 + r) * 64 + et * 16 + l16;
                    outp[idx] = acc[dt][et][r] + scratch[idx];
                }
    }
    if (t < 64) ks_part[(size_t)blockIdx.x * 48 * 64 + bh * 64 + t] =
        ksred[0][t] + ksred[1][t] + ksred[2][t] + ksred[3][t];
}

// ---------- out_pre[b,n,h*64+e] = (q[n,:] @ kv) / (q[n,:]·ksum + 1e-6), bf16 ----------
__global__ __launch_bounds__(256) void attn_apply(const ushort* __restrict__ qkv,
                                                  const float* __restrict__ kv_part,
                                                  const float* __restrict__ ks_part,
                                                  ushort* __restrict__ outpre) {
    __shared__ ushort kvb[64 * 80];
    const int bh = blockIdx.y, b = bh / NH, h = bh % NH;
    const int t = threadIdx.x, w = t >> 6, lane = t & 63, l16 = lane & 15, quad = lane >> 4;

    for (int i = t; i < 4096; i += 256) {
        float s = 0.f;
        #pragma unroll
        for (int c = 0; c < 8; c++) s += kv_part[((size_t)c * 48 + bh) * 4096 + i];
        kvb[(i >> 6) * 80 + (i & 63)] = f2bf(s);
    }
    for (int i = t; i < 1024; i += 256) {
        const int d = i >> 4, c = i & 15;
        float s = 0.f;
        if (c == 0) {
            #pragma unroll
            for (int cc = 0; cc < 8; cc++) s += ks_part[(size_t)cc * 48 * 64 + bh * 64 + d];
        }
        kvb[d * 80 + 64 + c] = (c == 0) ? f2bf(s) : (ushort)0;
    }
    __syncthreads();

    short8 bfr[5][2];
    #pragma unroll
    for (int et = 0; et < 5; et++)
        #pragma unroll
        for (int ks = 0; ks < 2; ks++) {
            short8 v;
            #pragma unroll
            for (int j = 0; j < 8; j++)
                v[j] = (short)kvb[(ks * 32 + quad * 8 + j) * 80 + et * 16 + l16];
            bfr[et][ks] = v;
        }

    const ushort* qbase = qkv + (size_t)(b * NN) * LDQKV + h * ND;
    ushort* obase = outpre + (size_t)(b * NN) * NC + h * ND;
    const int n0 = blockIdx.x * 1024;

    for (int it = 0; it < 16; it++) {
        const int nt = n0 + (it * 4 + w) * 16;
        const ushort* qp = qbase + (size_t)(nt + l16) * LDQKV + quad * 8;
        const short8 a0 = *(const short8*)qp;
        const short8 a1 = *(const short8*)(qp + 32);
        floatx4 acc[5] = {};
        #pragma unroll
        for (int et = 0; et < 5; et++) {
            acc[et] = __builtin_amdgcn_mfma_f32_16x16x32_bf16(a0, bfr[et][0], acc[et], 0, 0, 0);
            acc[et] = __builtin_amdgcn_mfma_f32_16x16x32_bf16(a1, bfr[et][1], acc[et], 0, 0, 0);
        }
        float dv[4];
        #pragma unroll
        for (int r = 0; r < 4; r++) dv[r] = __shfl(acc[4][r], lane & 48);
        #pragma unroll
        for (int et = 0; et < 4; et++)
            #pragma unroll
            for (int r = 0; r < 4; r++) {
                const float o = acc[et][r] / (dv[r] + 1e-6f);
                obase[(size_t)(nt + quad * 4 + r) * NC + et * 16 + l16] = f2bf(o);
            }
    }
}

extern "C" void kernel_launch(void* const* d_in, const int* in_sizes, int n_in,
                              void* d_out, int out_size, void* d_ws, size_t ws_size,
                              hipStream_t stream) {
    (void)in_sizes; (void)n_in; (void)out_size; (void)ws_size;
    const float* X     = (const float*)d_in[0];   // [4,8192,768] fp32
    const float* Wqkv  = (const float*)d_in[1];   // [2304,768]   fp32
    const float* Wproj = (const float*)d_in[2];   // [768,768]    fp32
    const float* bproj = (const float*)d_in[3];   // [768]        fp32
    float* out = (float*)d_out;                   // [4,8192,768] fp32

    char* ws = (char*)d_ws;
    size_t off = 0;
    ushort* qkv     = (ushort*)(ws + off); off += (size_t)32768 * 2304 * 2;  // 150,994,944
    ushort* outpre  = (ushort*)(ws + off); off += (size_t)32768 * 768 * 2;   //  50,331,648
    ushort* xbf     = (ushort*)(ws + off); off += (size_t)32768 * 768 * 2;   //  50,331,648
    ushort* wqkvbf  = (ushort*)(ws + off); off += (size_t)2304 * 768 * 2;    //   3,538,944
    ushort* wprojbf = (ushort*)(ws + off);                                    //   1,179,648
    // kv/ks partials alias xbf's space: xbf is dead once the QKV GEMM finishes,
    // kv_ksum runs strictly after it (stream order).  6.34 MB << 50 MB.
    float* kv_part = (float*)xbf;                          // [8][48][4096] f32
    float* ks_part = kv_part + (size_t)8 * 48 * 4096;      // [8][48][64]   f32

    const int nx = 32768 * 768, nwq = 2304 * 768, nwp = 768 * 768;
    cvt_bf16<<<nx  / (256 * 8), 256, 0, stream>>>(X,     xbf,     nx);
    cvt_bf16<<<nwq / (256 * 8), 256, 0, stream>>>(Wqkv,  wqkvbf,  nwq);
    cvt_bf16<<<nwp / (256 * 8), 256, 0, stream>>>(Wproj, wprojbf, nwp);

    // QKV: M=32768, N=2304 -> grid 9 x 128 = 1152 wgs (%8==0 for XCD swizzle)
    gemm256<LDQKV, true, false, ushort><<<dim3(9, 128), 512, 0, stream>>>(xbf, wqkvbf, nullptr, qkv, NC);
    kv_ksum<<<dim3(8, 48), 256, 0, stream>>>(qkv, kv_part, ks_part);
    attn_apply<<<dim3(8, 48), 256, 0, stream>>>(qkv, kv_part, ks_part, outpre);
    // proj: M=32768, N=768 -> grid 6 x 256 = 1536 blocks, 2/CU -> 3 exact gens
    gemm_bt<NC, false, true, float><<<dim3(6, 256), 256, 0, stream>>>(outpre, wprojbf, bproj, out, NC);
}

// Round 7
// 447.045 us; speedup vs baseline: 1.0119x; 1.0119x over previous
//
#include <hip/hip_runtime.h>
#include <hip/hip_bf16.h>
#include <stdint.h>

typedef __attribute__((ext_vector_type(8))) short short8;
typedef __attribute__((ext_vector_type(4))) float floatx4;

#define NB 4
#define NN 8192
#define NC 768
#define NH 12
#define ND 64
#define LDQKV 2304
#define NCH 16   // n-chunks for kv_ksum / attn_apply (16x48=768 blocks = 3 exact gens)

// ---------- helpers ----------
__device__ __forceinline__ float bf2f(ushort u) {
    union { float f; uint32_t i; } x; x.i = ((uint32_t)u) << 16; return x.f;
}
__device__ __forceinline__ ushort f2bf(float f) {
    union { float f; uint32_t i; } x; x.f = f;
    uint32_t r = x.i + 0x7fff + ((x.i >> 16) & 1);
    return (ushort)(r >> 16);
}
// async global->LDS, 16B per lane: lane i lands at ldsbase + 16*i (wave-uniform base).
typedef const __attribute__((address_space(1))) uint32_t* gas1_t;
typedef __attribute__((address_space(3))) uint32_t* las3_t;
__device__ __forceinline__ void gl_lds16(const void* g, const void* l) {
    __builtin_amdgcn_global_load_lds((gas1_t)(uintptr_t)g,
                                     (las3_t)(uint32_t)(uintptr_t)l, 16, 0, 0);
}

// ---------- fp32 -> bf16 bulk convert (8 elems/thread, 16B stores) ----------
__global__ __launch_bounds__(256) void cvt_bf16(const float* __restrict__ src,
                                                ushort* __restrict__ dst, int n) {
    const int i = (blockIdx.x * 256 + threadIdx.x) * 8;
    if (i >= n) return;
    const float4 a = *(const float4*)(src + i);
    const float4 b = *(const float4*)(src + i + 4);
    short8 v;
    v[0] = (short)f2bf(a.x); v[1] = (short)f2bf(a.y);
    v[2] = (short)f2bf(a.z); v[3] = (short)f2bf(a.w);
    v[4] = (short)f2bf(b.x); v[5] = (short)f2bf(b.y);
    v[6] = (short)f2bf(b.z); v[7] = (short)f2bf(b.w);
    *(short8*)(dst + i) = v;
}

// ============ 256x256 8-phase GEMM (QKV): C = act(A @ Bw^T) ============
// FROZEN schedule (R1/R3, measured 156 us): two-barrier phase lockstep,
// stages spread 2-2-2-2 across phases, lead-1 A / lead-2 B, vmcnt(4) at ph3.
// R2 (hoisted reads) and R4 (lead-2 everything) both regressed — do not deviate.

// stage one 128x64 half-tile (2 x gl_lds16 per thread), source-side swizzle
__device__ __forceinline__ void stage_half(const ushort* __restrict__ src, int row0,
                                           int k0, int K, ushort* dst, int t, int w) {
    const int rsub = t >> 3;                       // 0..63
    const int ch = (t & 7) ^ (rsub & 7);           // inverse of read-side XOR
    const ushort* g0 = src + (size_t)(row0 + rsub) * K + k0 + ch * 8;
    gl_lds16(g0,                 dst + w * 512);
    gl_lds16(g0 + (size_t)64 * K, dst + 4096 + w * 512);
}

#define PHASE_SYNC() do {                                        \
    __builtin_amdgcn_s_barrier();                                \
    asm volatile("s_waitcnt lgkmcnt(0)" ::: "memory");           \
    __builtin_amdgcn_sched_barrier(0);                           \
} while (0)

template<int LDC, bool ELU, bool BIAS, typename OutT>
__global__ __launch_bounds__(512) void gemm256(const ushort* __restrict__ A,
                                               const ushort* __restrict__ Bw,
                                               const float* __restrict__ bias,
                                               OutT* __restrict__ Cout, int K) {
    __shared__ __align__(16) ushort SL[2][4][8192];   // [buf][region][128*64]
    const int t = threadIdx.x, w = t >> 6, lane = t & 63;
    const int l16 = lane & 15, quad = lane >> 4;
    const int wm = w >> 2, wn = w & 3;
    const int bro = (wn & 1) * 64;                    // row offset inside B region

    const int gx = gridDim.x;
    const int nwg = gx * gridDim.y;
    int bid = blockIdx.y * gx + blockIdx.x;
    bid = (bid & 7) * (nwg >> 3) + (bid >> 3);        // XCD swizzle (nwg % 8 == 0)
    const int m0 = (bid / gx) * 256;
    const int n0 = (bid % gx) * 256;
    const int NT = K >> 6;                            // K-tiles of 64 (NT >= 3)

    floatx4 acc[8][4] = {};
    short8 af[4][2], b01[2][2], b23[2][2];

    // prologue: K0 {B0,B1,A0,A1}, K1 {B0,B1}  -> 12 loads/thread
    stage_half(Bw, n0,       0,  K, &SL[0][0][0], t, w);
    stage_half(Bw, n0 + 128, 0,  K, &SL[0][1][0], t, w);
    stage_half(A,  m0,       0,  K, &SL[0][2][0], t, w);
    stage_half(A,  m0 + 128, 0,  K, &SL[0][3][0], t, w);
    stage_half(Bw, n0,       64, K, &SL[1][0][0], t, w);
    stage_half(Bw, n0 + 128, 64, K, &SL[1][1][0], t, w);
    asm volatile("s_waitcnt vmcnt(4)" ::: "memory");  // K0 fully resident
    __builtin_amdgcn_s_barrier();

    for (int j = 0; j < NT; j++) {
        const int buf = j & 1;
        const ushort* As = &SL[buf][2 + wm][0];
        const ushort* Bs = &SL[buf][wn >> 1][0];

        // ---- phase 0: read A(m_lo) + B(n0,n1) [12 ds_reads]; stage A-lo(j+1)
        #pragma unroll
        for (int mi = 0; mi < 4; mi++) {
            const int row = mi * 16 + l16;
            const int sw = (row & 7) << 3;
            const int base = row * 64 + quad * 8;
            af[mi][0] = *(const short8*)&As[base ^ sw];
            af[mi][1] = *(const short8*)&As[(base + 32) ^ sw];
        }
        #pragma unroll
        for (int ni = 0; ni < 2; ni++) {
            const int row = bro + ni * 16 + l16;
            const int sw = (row & 7) << 3;
            const int base = row * 64 + quad * 8;
            b01[ni][0] = *(const short8*)&Bs[base ^ sw];
            b01[ni][1] = *(const short8*)&Bs[(base + 32) ^ sw];
        }
        if (j + 1 < NT) stage_half(A, m0, (j + 1) * 64, K, &SL[buf ^ 1][2][0], t, w);
        asm volatile("s_waitcnt lgkmcnt(8)" ::: "memory");  // template hint: 12 reads issued
        PHASE_SYNC();
        __builtin_amdgcn_s_setprio(1);
        #pragma unroll
        for (int mi = 0; mi < 4; mi++)
            #pragma unroll
            for (int ni = 0; ni < 2; ni++) {
                acc[mi][ni] = __builtin_amdgcn_mfma_f32_16x16x32_bf16(af[mi][0], b01[ni][0], acc[mi][ni], 0, 0, 0);
                acc[mi][ni] = __builtin_amdgcn_mfma_f32_16x16x32_bf16(af[mi][1], b01[ni][1], acc[mi][ni], 0, 0, 0);
            }
        __builtin_amdgcn_s_setprio(0);
        __builtin_amdgcn_s_barrier();

        // ---- phase 1: read B(n2,n3); stage A-hi(j+1); MFMA m_lo x n23
        #pragma unroll
        for (int ni = 0; ni < 2; ni++) {
            const int row = bro + (2 + ni) * 16 + l16;
            const int sw = (row & 7) << 3;
            const int base = row * 64 + quad * 8;
            b23[ni][0] = *(const short8*)&Bs[base ^ sw];
            b23[ni][1] = *(const short8*)&Bs[(base + 32) ^ sw];
        }
        if (j + 1 < NT) stage_half(A, m0 + 128, (j + 1) * 64, K, &SL[buf ^ 1][3][0], t, w);
        PHASE_SYNC();
        __builtin_amdgcn_s_setprio(1);
        #pragma unroll
        for (int mi = 0; mi < 4; mi++)
            #pragma unroll
            for (int ni = 0; ni < 2; ni++) {
                acc[mi][2 + ni] = __builtin_amdgcn_mfma_f32_16x16x32_bf16(af[mi][0], b23[ni][0], acc[mi][2 + ni], 0, 0, 0);
                acc[mi][2 + ni] = __builtin_amdgcn_mfma_f32_16x16x32_bf16(af[mi][1], b23[ni][1], acc[mi][2 + ni], 0, 0, 0);
            }
        __builtin_amdgcn_s_setprio(0);
        __builtin_amdgcn_s_barrier();

        // ---- phase 2: read A(m_hi); stage B-lo(j+2); MFMA m_hi x n01
        #pragma unroll
        for (int mi = 0; mi < 4; mi++) {
            const int row = (4 + mi) * 16 + l16;
            const int sw = (row & 7) << 3;
            const int base = row * 64 + quad * 8;
            af[mi][0] = *(const short8*)&As[base ^ sw];
            af[mi][1] = *(const short8*)&As[(base + 32) ^ sw];
        }
        if (j + 2 < NT) stage_half(Bw, n0, (j + 2) * 64, K, &SL[buf][0][0], t, w);
        PHASE_SYNC();
        __builtin_amdgcn_s_setprio(1);
        #pragma unroll
        for (int mi = 0; mi < 4; mi++)
            #pragma unroll
            for (int ni = 0; ni < 2; ni++) {
                acc[4 + mi][ni] = __builtin_amdgcn_mfma_f32_16x16x32_bf16(af[mi][0], b01[ni][0], acc[4 + mi][ni], 0, 0, 0);
                acc[4 + mi][ni] = __builtin_amdgcn_mfma_f32_16x16x32_bf16(af[mi][1], b01[ni][1], acc[4 + mi][ni], 0, 0, 0);
            }
        __builtin_amdgcn_s_setprio(0);
        __builtin_amdgcn_s_barrier();

        // ---- phase 3: stage B-hi(j+2); MFMA m_hi x n23; boundary vmcnt
        if (j + 2 < NT) stage_half(Bw, n0 + 128, (j + 2) * 64, K, &SL[buf][1][0], t, w);
        __builtin_amdgcn_s_barrier();
        __builtin_amdgcn_s_setprio(1);
        #pragma unroll
        for (int mi = 0; mi < 4; mi++)
            #pragma unroll
            for (int ni = 0; ni < 2; ni++) {
                acc[4 + mi][2 + ni] = __builtin_amdgcn_mfma_f32_16x16x32_bf16(af[mi][0], b23[ni][0], acc[4 + mi][2 + ni], 0, 0, 0);
                acc[4 + mi][2 + ni] = __builtin_amdgcn_mfma_f32_16x16x32_bf16(af[mi][1], b23[ni][1], acc[4 + mi][2 + ni], 0, 0, 0);
            }
        __builtin_amdgcn_s_setprio(0);
        // tile j+1 must be resident after this barrier; leave B(j+2) in flight
        if (j < NT - 2) asm volatile("s_waitcnt vmcnt(4)" ::: "memory");
        else            asm volatile("s_waitcnt vmcnt(0)" ::: "memory");
        __builtin_amdgcn_s_barrier();
    }

    // ---- epilogue
    #pragma unroll
    for (int mi = 0; mi < 8; mi++) {
        const int row = m0 + wm * 128 + mi * 16 + quad * 4;
        #pragma unroll
        for (int n = 0; n < 4; n++) {
            const int col = n0 + wn * 64 + n * 16 + l16;
            float bval = 0.f;
            if (BIAS) bval = bias[col];
            #pragma unroll
            for (int r = 0; r < 4; r++) {
                float v = acc[mi][n][r];
                if (ELU) { if (col < 2 * NC) v = (v > 0.f) ? v + 1.f : __expf(v); }
                if (BIAS) v += bval;
                if (sizeof(OutT) == 2) Cout[(size_t)(row + r) * LDC + col] = (OutT)f2bf(v);
                else                   Cout[(size_t)(row + r) * LDC + col] = (OutT)v;
            }
        }
    }
}

// ============ 128x128 2-phase GEMM (proj): better tail at small N ============
// 256 threads (4 waves, 2x2), 4x4 16x16x32 MFMA per wave, BK=32, 16 KiB LDS
// -> 2 blocks/CU; grid 6x256 = 1536 blocks = 3 exact generations.
template<int LDC, bool ELU, bool BIAS, typename OutT>
__global__ __launch_bounds__(256) void gemm_bt(const ushort* __restrict__ A,
                                               const ushort* __restrict__ Bw,
                                               const float* __restrict__ bias,
                                               OutT* __restrict__ Cout, int K) {
    __shared__ ushort As[128 * 32];
    __shared__ ushort Bs[128 * 32];
    const int t = threadIdx.x;
    const int w = t >> 6, lane = t & 63, l16 = lane & 15, quad = lane >> 4;
    const int wm = w & 1, wn = w >> 1;
    const int m0 = blockIdx.y * 128, n0 = blockIdx.x * 128;

    floatx4 acc[4][4] = {};

    const int rowA = t >> 2, chA = t & 3;            // 64 rows x 4 chunks of 16B
    const ushort* gA = A  + (size_t)(m0 + rowA) * K + chA * 8;
    const ushort* gB = Bw + (size_t)(n0 + rowA) * K + chA * 8;

    for (int k0 = 0; k0 < K; k0 += 32) {
        gl_lds16(gA + k0,                As + w * 512);
        gl_lds16(gA + k0 + 64 * K,       As + 2048 + w * 512);
        gl_lds16(gB + k0,                Bs + w * 512);
        gl_lds16(gB + k0 + 64 * K,       Bs + 2048 + w * 512);
        __syncthreads();
        short8 af[4], bfr[4];
        #pragma unroll
        for (int i = 0; i < 4; i++)
            af[i] = *(const short8*)&As[(wm * 64 + i * 16 + l16) * 32 + quad * 8];
        #pragma unroll
        for (int j = 0; j < 4; j++)
            bfr[j] = *(const short8*)&Bs[(wn * 64 + j * 16 + l16) * 32 + quad * 8];
        #pragma unroll
        for (int i = 0; i < 4; i++)
            #pragma unroll
            for (int j = 0; j < 4; j++)
                acc[i][j] = __builtin_amdgcn_mfma_f32_16x16x32_bf16(af[i], bfr[j], acc[i][j], 0, 0, 0);
        __syncthreads();
    }

    #pragma unroll
    for (int i = 0; i < 4; i++) {
        const int row = m0 + wm * 64 + i * 16 + quad * 4;
        #pragma unroll
        for (int j = 0; j < 4; j++) {
            const int col = n0 + wn * 64 + j * 16 + l16;
            float bval = 0.f;
            if (BIAS) bval = bias[col];
            #pragma unroll
            for (int r = 0; r < 4; r++) {
                float v = acc[i][j][r];
                if (ELU) { if (col < 2 * NC) v = (v > 0.f) ? v + 1.f : __expf(v); }
                if (BIAS) v += bval;
                if (sizeof(OutT) == 2) Cout[(size_t)(row + r) * LDC + col] = (OutT)f2bf(v);
                else                   Cout[(size_t)(row + r) * LDC + col] = (OutT)v;
            }
        }
    }
}

// ---------- kv_part[c][bh][d][e] = sum_n k[n,d] v[n,e] over n-chunk c; also ksum ----------
// atomics-free; ksum via MFMA vs all-ones. Counted-vmcnt double-buffered staging
// (kept from R4: −21 us). Grid 16x48 = 768 blocks = 3 exact generations;
// each block: 512 rows = 4 stages of 128.
__global__ __launch_bounds__(256) void kv_ksum(const ushort* __restrict__ qkv,
                                               float* __restrict__ kv_part,
                                               float* __restrict__ ks_part) {
    __shared__ ushort kvsh[2][2][128 * 64];   // [buf][k/v][...]; reused as f32 scratch
    __shared__ float  ksred[4][64];
    const int bh = blockIdx.y, b = bh / NH, h = bh % NH;
    const int t = threadIdx.x, w = t >> 6, lane = t & 63, l16 = lane & 15, quad = lane >> 4;
    const int n0 = blockIdx.x * (NN / NCH);   // 512 rows per chunk (R5 bug: was *510)
    const ushort* kbase = qkv + (size_t)(b * NN) * LDQKV + NC     + h * ND;
    const ushort* vbase = qkv + (size_t)(b * NN) * LDQKV + 2 * NC + h * ND;

    floatx4 acc[4][4] = {};
    floatx4 aks[4] = {};
    short8 bones;
    #pragma unroll
    for (int j = 0; j < 8; j++) bones[j] = (short)0x3F80;   // bf16 1.0
    const int rowT = t >> 3, ch = t & 7;   // 32 rows x 8 chunks of 16B per issue

    // stage chunk s into buffer s&1 (8 gl_lds/thread)
    #define KV_STAGE(s) do {                                                  \
        const int nb_ = n0 + (s) * 128;                                       \
        _Pragma("unroll")                                                     \
        for (int i_ = 0; i_ < 4; i_++) {                                      \
            const size_t r_ = (size_t)(nb_ + i_ * 32 + rowT) * LDQKV + ch * 8;\
            gl_lds16(kbase + r_, &kvsh[(s) & 1][0][0] + i_ * 2048 + w * 512); \
            gl_lds16(vbase + r_, &kvsh[(s) & 1][1][0] + i_ * 2048 + w * 512); \
        }                                                                     \
    } while (0)

    KV_STAGE(0);
    for (int s = 0; s < 4; s++) {
        if (s < 3) KV_STAGE(s + 1);
        if (s < 3) asm volatile("s_waitcnt vmcnt(8)" ::: "memory");
        else       asm volatile("s_waitcnt vmcnt(0)" ::: "memory");
        __builtin_amdgcn_s_barrier();
        const ushort* klds = &kvsh[s & 1][0][0];
        const ushort* vlds = &kvsh[s & 1][1][0];
        short8 af[4], bfr[4];
        #pragma unroll
        for (int dt = 0; dt < 4; dt++) {
            short8 v;
            #pragma unroll
            for (int j = 0; j < 8; j++)
                v[j] = (short)klds[(w * 32 + quad * 8 + j) * 64 + dt * 16 + l16];
            af[dt] = v;
        }
        #pragma unroll
        for (int et = 0; et < 4; et++) {
            short8 v;
            #pragma unroll
            for (int j = 0; j < 8; j++)
                v[j] = (short)vlds[(w * 32 + quad * 8 + j) * 64 + et * 16 + l16];
            bfr[et] = v;
        }
        #pragma unroll
        for (int dt = 0; dt < 4; dt++) {
            #pragma unroll
            for (int et = 0; et < 4; et++)
                acc[dt][et] = __builtin_amdgcn_mfma_f32_16x16x32_bf16(af[dt], bfr[et], acc[dt][et], 0, 0, 0);
            aks[dt] = __builtin_amdgcn_mfma_f32_16x16x32_bf16(af[dt], bones, aks[dt], 0, 0, 0);
        }
        __builtin_amdgcn_s_barrier();   // buf s&1 reads done before stage(s+2) next iter
    }
    #undef KV_STAGE

    // ksum wave partials: lane l16==0 holds ksum[dt*16+quad*4+r] (dup over cols)
    if (l16 == 0) {
        #pragma unroll
        for (int dt = 0; dt < 4; dt++)
            #pragma unroll
            for (int r = 0; r < 4; r++)
                ksred[w][dt * 16 + quad * 4 + r] = aks[dt][r];
    }

    // kv barrier-tree reduce across the 4 waves via LDS scratch (no atomics)
    float* scratch = (float*)kvsh;         // 8192 floats needed, 64 KB available
    if (w >= 2) {
        float* dst = scratch + (w - 2) * 4096;
        #pragma unroll
        for (int dt = 0; dt < 4; dt++)
            #pragma unroll
            for (int et = 0; et < 4; et++)
                #pragma unroll
                for (int r = 0; r < 4; r++)
                    dst[(dt * 16 + quad * 4 + r) * 64 + et * 16 + l16] = acc[dt][et][r];
    }
    __syncthreads();
    if (w < 2) {
        const float* srcp = scratch + w * 4096;
        #pragma unroll
        for (int dt = 0; dt < 4; dt++)
            #pragma unroll
            for (int et = 0; et < 4; et++)
                #pragma unroll
                for (int r = 0; r < 4; r++)
                    acc[dt][et][r] += srcp[(dt * 16 + quad * 4 + r) * 64 + et * 16 + l16];
    }
    __syncthreads();
    if (w == 1) {
        #pragma unroll
        for (int dt = 0; dt < 4; dt++)
            #pragma unroll
            for (int et = 0; et < 4; et++)
                #pragma unroll
                for (int r = 0; r < 4; r++)
                    scratch[(dt * 16 + quad * 4 + r) * 64 + et * 16 + l16] = acc[dt][et][r];
    }
    __syncthreads();
    if (w == 0) {
        float* outp = kv_part + ((size_t)blockIdx.x * 48 + bh) * 4096;
        #pragma unroll
        for (int dt = 0; dt < 4; dt++)
            #pragma unroll
            for (int et = 0; et < 4; et++)
                #pragma unroll
                for (int r = 0; r < 4; r++) {
                    const int idx = (dt * 16 + quad * 4 + r) * 64 + et * 16 + l16;
                    outp[idx] = acc[dt][et][r] + scratch[idx];
                }
    }
    if (t < 64) ks_part[(size_t)blockIdx.x * 48 * 64 + bh * 64 + t] =
        ksred[0][t] + ksred[1][t] + ksred[2][t] + ksred[3][t];
}

// ---------- out_pre[b,n,h*64+e] = (q[n,:] @ kv) / (q[n,:]·ksum + 1e-6), bf16 ----------
// Grid 16x48 = 768 blocks = 3 exact generations; 512 rows/block.
__global__ __launch_bounds__(256) void attn_apply(const ushort* __restrict__ qkv,
                                                  const float* __restrict__ kv_part,
                                                  const float* __restrict__ ks_part,
                                                  ushort* __restrict__ outpre) {
    __shared__ ushort kvb[64 * 80];
    const int bh = blockIdx.y, b = bh / NH, h = bh % NH;
    const int t = threadIdx.x, w = t >> 6, lane = t & 63, l16 = lane & 15, quad = lane >> 4;

    for (int i = t; i < 4096; i += 256) {
        float s = 0.f;
        #pragma unroll
        for (int c = 0; c < NCH; c++) s += kv_part[((size_t)c * 48 + bh) * 4096 + i];
        kvb[(i >> 6) * 80 + (i & 63)] = f2bf(s);
    }
    for (int i = t; i < 1024; i += 256) {
        const int d = i >> 4, c = i & 15;
        float s = 0.f;
        if (c == 0) {
            #pragma unroll
            for (int cc = 0; cc < NCH; cc++) s += ks_part[(size_t)cc * 48 * 64 + bh * 64 + d];
        }
        kvb[d * 80 + 64 + c] = (c == 0) ? f2bf(s) : (ushort)0;
    }
    __syncthreads();

    short8 bfr[5][2];
    #pragma unroll
    for (int et = 0; et < 5; et++)
        #pragma unroll
        for (int ks = 0; ks < 2; ks++) {
            short8 v;
            #pragma unroll
            for (int j = 0; j < 8; j++)
                v[j] = (short)kvb[(ks * 32 + quad * 8 + j) * 80 + et * 16 + l16];
            bfr[et][ks] = v;
        }

    const ushort* qbase = qkv + (size_t)(b * NN) * LDQKV + h * ND;
    ushort* obase = outpre + (size_t)(b * NN) * NC + h * ND;
    const int n0 = blockIdx.x * (NN / NCH);   // 512 rows/block

    for (int it = 0; it < 8; it++) {
        const int nt = n0 + (it * 4 + w) * 16;
        const ushort* qp = qbase + (size_t)(nt + l16) * LDQKV + quad * 8;
        const short8 a0 = *(const short8*)qp;
        const short8 a1 = *(const short8*)(qp + 32);
        floatx4 acc[5] = {};
        #pragma unroll
        for (int et = 0; et < 5; et++) {
            acc[et] = __builtin_amdgcn_mfma_f32_16x16x32_bf16(a0, bfr[et][0], acc[et], 0, 0, 0);
            acc[et] = __builtin_amdgcn_mfma_f32_16x16x32_bf16(a1, bfr[et][1], acc[et], 0, 0, 0);
        }
        float dv[4];
        #pragma unroll
        for (int r = 0; r < 4; r++) dv[r] = __shfl(acc[4][r], lane & 48);
        #pragma unroll
        for (int et = 0; et < 4; et++)
            #pragma unroll
            for (int r = 0; r < 4; r++) {
                const float o = acc[et][r] / (dv[r] + 1e-6f);
                obase[(size_t)(nt + quad * 4 + r) * NC + et * 16 + l16] = f2bf(o);
            }
    }
}

extern "C" void kernel_launch(void* const* d_in, const int* in_sizes, int n_in,
                              void* d_out, int out_size, void* d_ws, size_t ws_size,
                              hipStream_t stream) {
    (void)in_sizes; (void)n_in; (void)out_size; (void)ws_size;
    const float* X     = (const float*)d_in[0];   // [4,8192,768] fp32
    const float* Wqkv  = (const float*)d_in[1];   // [2304,768]   fp32
    const float* Wproj = (const float*)d_in[2];   // [768,768]    fp32
    const float* bproj = (const float*)d_in[3];   // [768]        fp32
    float* out = (float*)d_out;                   // [4,8192,768] fp32

    char* ws = (char*)d_ws;
    size_t off = 0;
    ushort* qkv     = (ushort*)(ws + off); off += (size_t)32768 * 2304 * 2;  // 150,994,944
    ushort* outpre  = (ushort*)(ws + off); off += (size_t)32768 * 768 * 2;   //  50,331,648
    ushort* xbf     = (ushort*)(ws + off); off += (size_t)32768 * 768 * 2;   //  50,331,648
    ushort* wqkvbf  = (ushort*)(ws + off); off += (size_t)2304 * 768 * 2;    //   3,538,944
    ushort* wprojbf = (ushort*)(ws + off);                                    //   1,179,648
    // kv/ks partials alias xbf's space: xbf is dead once the QKV GEMM finishes,
    // kv_ksum runs strictly after it (stream order).  12.8 MB << 50 MB.
    float* kv_part = (float*)xbf;                          // [16][48][4096] f32
    float* ks_part = kv_part + (size_t)NCH * 48 * 4096;    // [16][48][64]   f32

    const int nx = 32768 * 768, nwq = 2304 * 768, nwp = 768 * 768;
    cvt_bf16<<<nx  / (256 * 8), 256, 0, stream>>>(X,     xbf,     nx);
    cvt_bf16<<<nwq / (256 * 8), 256, 0, stream>>>(Wqkv,  wqkvbf,  nwq);
    cvt_bf16<<<nwp / (256 * 8), 256, 0, stream>>>(Wproj, wprojbf, nwp);

    // QKV: M=32768, N=2304 -> grid 9 x 128 = 1152 wgs (%8==0 for XCD swizzle)
    gemm256<LDQKV, true, false, ushort><<<dim3(9, 128), 512, 0, stream>>>(xbf, wqkvbf, nullptr, qkv, NC);
    kv_ksum<<<dim3(NCH, 48), 256, 0, stream>>>(qkv, kv_part, ks_part);
    attn_apply<<<dim3(NCH, 48), 256, 0, stream>>>(qkv, kv_part, ks_part, outpre);
    // proj: M=32768, N=768 -> grid 6 x 256 = 1536 blocks, 2/CU -> 3 exact gens
    gemm_bt<NC, false, true, float><<<dim3(6, 256), 256, 0, stream>>>(outpre, wprojbf, bproj, out, NC);
}

// Round 8
// 440.637 us; speedup vs baseline: 1.0266x; 1.0145x over previous
//
#include <hip/hip_runtime.h>
#include <hip/hip_bf16.h>
#include <stdint.h>

typedef __attribute__((ext_vector_type(8))) short short8;
typedef __attribute__((ext_vector_type(4))) float floatx4;

#define NB 4
#define NN 8192
#define NC 768
#define NH 12
#define ND 64
#define LDQKV 2304
#define NCH 8    // n-chunks for kv_ksum / attn_apply (R4-measured optimum; NCH=16 cost +26us)

// ---------- helpers ----------
__device__ __forceinline__ float bf2f(ushort u) {
    union { float f; uint32_t i; } x; x.i = ((uint32_t)u) << 16; return x.f;
}
__device__ __forceinline__ ushort f2bf(float f) {
    union { float f; uint32_t i; } x; x.f = f;
    uint32_t r = x.i + 0x7fff + ((x.i >> 16) & 1);
    return (ushort)(r >> 16);
}
// async global->LDS, 16B per lane: lane i lands at ldsbase + 16*i (wave-uniform base).
typedef const __attribute__((address_space(1))) uint32_t* gas1_t;
typedef __attribute__((address_space(3))) uint32_t* las3_t;
__device__ __forceinline__ void gl_lds16(const void* g, const void* l) {
    __builtin_amdgcn_global_load_lds((gas1_t)(uintptr_t)g,
                                     (las3_t)(uint32_t)(uintptr_t)l, 16, 0, 0);
}

// ---------- fp32 -> bf16 bulk convert, 3 segments in one launch ----------
__device__ __forceinline__ void cvt8(const float* __restrict__ src,
                                     ushort* __restrict__ dst, int i) {
    const float4 a = *(const float4*)(src + i);
    const float4 b = *(const float4*)(src + i + 4);
    short8 v;
    v[0] = (short)f2bf(a.x); v[1] = (short)f2bf(a.y);
    v[2] = (short)f2bf(a.z); v[3] = (short)f2bf(a.w);
    v[4] = (short)f2bf(b.x); v[5] = (short)f2bf(b.y);
    v[6] = (short)f2bf(b.z); v[7] = (short)f2bf(b.w);
    *(short8*)(dst + i) = v;
}
// segment block counts (2048 elems per block)
#define CVT_NB0 (32768 * 768 / 2048)   // X    : 12288
#define CVT_NB1 (2304 * 768 / 2048)    // Wqkv :   864
#define CVT_NB2 (768 * 768 / 2048)     // Wproj:   288
__global__ __launch_bounds__(256) void cvt_bf16_3(const float* __restrict__ s0, ushort* __restrict__ d0,
                                                  const float* __restrict__ s1, ushort* __restrict__ d1,
                                                  const float* __restrict__ s2, ushort* __restrict__ d2) {
    int blk = blockIdx.x;
    if (blk < CVT_NB0) { cvt8(s0, d0, (blk * 256 + threadIdx.x) * 8); return; }
    blk -= CVT_NB0;
    if (blk < CVT_NB1) { cvt8(s1, d1, (blk * 256 + threadIdx.x) * 8); return; }
    blk -= CVT_NB1;
    cvt8(s2, d2, (blk * 256 + threadIdx.x) * 8);
}

// ============ 256x256 8-phase GEMM (QKV): C = act(A @ Bw^T) ============
// FROZEN schedule (R1/R3, measured 156 us): two-barrier phase lockstep,
// stages spread 2-2-2-2 across phases, lead-1 A / lead-2 B, vmcnt(4) at ph3.
// R2 (hoisted reads) and R4 (lead-2 everything) both regressed — do not deviate.

// stage one 128x64 half-tile (2 x gl_lds16 per thread), source-side swizzle
__device__ __forceinline__ void stage_half(const ushort* __restrict__ src, int row0,
                                           int k0, int K, ushort* dst, int t, int w) {
    const int rsub = t >> 3;                       // 0..63
    const int ch = (t & 7) ^ (rsub & 7);           // inverse of read-side XOR
    const ushort* g0 = src + (size_t)(row0 + rsub) * K + k0 + ch * 8;
    gl_lds16(g0,                 dst + w * 512);
    gl_lds16(g0 + (size_t)64 * K, dst + 4096 + w * 512);
}

#define PHASE_SYNC() do {                                        \
    __builtin_amdgcn_s_barrier();                                \
    asm volatile("s_waitcnt lgkmcnt(0)" ::: "memory");           \
    __builtin_amdgcn_sched_barrier(0);                           \
} while (0)

template<int LDC, bool ELU, bool BIAS, typename OutT>
__global__ __launch_bounds__(512) void gemm256(const ushort* __restrict__ A,
                                               const ushort* __restrict__ Bw,
                                               const float* __restrict__ bias,
                                               OutT* __restrict__ Cout, int K) {
    __shared__ __align__(16) ushort SL[2][4][8192];   // [buf][region][128*64]
    const int t = threadIdx.x, w = t >> 6, lane = t & 63;
    const int l16 = lane & 15, quad = lane >> 4;
    const int wm = w >> 2, wn = w & 3;
    const int bro = (wn & 1) * 64;                    // row offset inside B region

    const int gx = gridDim.x;
    const int nwg = gx * gridDim.y;
    int bid = blockIdx.y * gx + blockIdx.x;
    bid = (bid & 7) * (nwg >> 3) + (bid >> 3);        // XCD swizzle (nwg % 8 == 0)
    const int m0 = (bid / gx) * 256;
    const int n0 = (bid % gx) * 256;
    const int NT = K >> 6;                            // K-tiles of 64 (NT >= 3)

    floatx4 acc[8][4] = {};
    short8 af[4][2], b01[2][2], b23[2][2];

    // prologue: K0 {B0,B1,A0,A1}, K1 {B0,B1}  -> 12 loads/thread
    stage_half(Bw, n0,       0,  K, &SL[0][0][0], t, w);
    stage_half(Bw, n0 + 128, 0,  K, &SL[0][1][0], t, w);
    stage_half(A,  m0,       0,  K, &SL[0][2][0], t, w);
    stage_half(A,  m0 + 128, 0,  K, &SL[0][3][0], t, w);
    stage_half(Bw, n0,       64, K, &SL[1][0][0], t, w);
    stage_half(Bw, n0 + 128, 64, K, &SL[1][1][0], t, w);
    asm volatile("s_waitcnt vmcnt(4)" ::: "memory");  // K0 fully resident
    __builtin_amdgcn_s_barrier();

    for (int j = 0; j < NT; j++) {
        const int buf = j & 1;
        const ushort* As = &SL[buf][2 + wm][0];
        const ushort* Bs = &SL[buf][wn >> 1][0];

        // ---- phase 0: read A(m_lo) + B(n0,n1) [12 ds_reads]; stage A-lo(j+1)
        #pragma unroll
        for (int mi = 0; mi < 4; mi++) {
            const int row = mi * 16 + l16;
            const int sw = (row & 7) << 3;
            const int base = row * 64 + quad * 8;
            af[mi][0] = *(const short8*)&As[base ^ sw];
            af[mi][1] = *(const short8*)&As[(base + 32) ^ sw];
        }
        #pragma unroll
        for (int ni = 0; ni < 2; ni++) {
            const int row = bro + ni * 16 + l16;
            const int sw = (row & 7) << 3;
            const int base = row * 64 + quad * 8;
            b01[ni][0] = *(const short8*)&Bs[base ^ sw];
            b01[ni][1] = *(const short8*)&Bs[(base + 32) ^ sw];
        }
        if (j + 1 < NT) stage_half(A, m0, (j + 1) * 64, K, &SL[buf ^ 1][2][0], t, w);
        asm volatile("s_waitcnt lgkmcnt(8)" ::: "memory");  // template hint: 12 reads issued
        PHASE_SYNC();
        __builtin_amdgcn_s_setprio(1);
        #pragma unroll
        for (int mi = 0; mi < 4; mi++)
            #pragma unroll
            for (int ni = 0; ni < 2; ni++) {
                acc[mi][ni] = __builtin_amdgcn_mfma_f32_16x16x32_bf16(af[mi][0], b01[ni][0], acc[mi][ni], 0, 0, 0);
                acc[mi][ni] = __builtin_amdgcn_mfma_f32_16x16x32_bf16(af[mi][1], b01[ni][1], acc[mi][ni], 0, 0, 0);
            }
        __builtin_amdgcn_s_setprio(0);
        __builtin_amdgcn_s_barrier();

        // ---- phase 1: read B(n2,n3); stage A-hi(j+1); MFMA m_lo x n23
        #pragma unroll
        for (int ni = 0; ni < 2; ni++) {
            const int row = bro + (2 + ni) * 16 + l16;
            const int sw = (row & 7) << 3;
            const int base = row * 64 + quad * 8;
            b23[ni][0] = *(const short8*)&Bs[base ^ sw];
            b23[ni][1] = *(const short8*)&Bs[(base + 32) ^ sw];
        }
        if (j + 1 < NT) stage_half(A, m0 + 128, (j + 1) * 64, K, &SL[buf ^ 1][3][0], t, w);
        PHASE_SYNC();
        __builtin_amdgcn_s_setprio(1);
        #pragma unroll
        for (int mi = 0; mi < 4; mi++)
            #pragma unroll
            for (int ni = 0; ni < 2; ni++) {
                acc[mi][2 + ni] = __builtin_amdgcn_mfma_f32_16x16x32_bf16(af[mi][0], b23[ni][0], acc[mi][2 + ni], 0, 0, 0);
                acc[mi][2 + ni] = __builtin_amdgcn_mfma_f32_16x16x32_bf16(af[mi][1], b23[ni][1], acc[mi][2 + ni], 0, 0, 0);
            }
        __builtin_amdgcn_s_setprio(0);
        __builtin_amdgcn_s_barrier();

        // ---- phase 2: read A(m_hi); stage B-lo(j+2); MFMA m_hi x n01
        #pragma unroll
        for (int mi = 0; mi < 4; mi++) {
            const int row = (4 + mi) * 16 + l16;
            const int sw = (row & 7) << 3;
            const int base = row * 64 + quad * 8;
            af[mi][0] = *(const short8*)&As[base ^ sw];
            af[mi][1] = *(const short8*)&As[(base + 32) ^ sw];
        }
        if (j + 2 < NT) stage_half(Bw, n0, (j + 2) * 64, K, &SL[buf][0][0], t, w);
        PHASE_SYNC();
        __builtin_amdgcn_s_setprio(1);
        #pragma unroll
        for (int mi = 0; mi < 4; mi++)
            #pragma unroll
            for (int ni = 0; ni < 2; ni++) {
                acc[4 + mi][ni] = __builtin_amdgcn_mfma_f32_16x16x32_bf16(af[mi][0], b01[ni][0], acc[4 + mi][ni], 0, 0, 0);
                acc[4 + mi][ni] = __builtin_amdgcn_mfma_f32_16x16x32_bf16(af[mi][1], b01[ni][1], acc[4 + mi][ni], 0, 0, 0);
            }
        __builtin_amdgcn_s_setprio(0);
        __builtin_amdgcn_s_barrier();

        // ---- phase 3: stage B-hi(j+2); MFMA m_hi x n23; boundary vmcnt
        if (j + 2 < NT) stage_half(Bw, n0 + 128, (j + 2) * 64, K, &SL[buf][1][0], t, w);
        __builtin_amdgcn_s_barrier();
        __builtin_amdgcn_s_setprio(1);
        #pragma unroll
        for (int mi = 0; mi < 4; mi++)
            #pragma unroll
            for (int ni = 0; ni < 2; ni++) {
                acc[4 + mi][2 + ni] = __builtin_amdgcn_mfma_f32_16x16x32_bf16(af[mi][0], b23[ni][0], acc[4 + mi][2 + ni], 0, 0, 0);
                acc[4 + mi][2 + ni] = __builtin_amdgcn_mfma_f32_16x16x32_bf16(af[mi][1], b23[ni][1], acc[4 + mi][2 + ni], 0, 0, 0);
            }
        __builtin_amdgcn_s_setprio(0);
        // tile j+1 must be resident after this barrier; leave B(j+2) in flight
        if (j < NT - 2) asm volatile("s_waitcnt vmcnt(4)" ::: "memory");
        else            asm volatile("s_waitcnt vmcnt(0)" ::: "memory");
        __builtin_amdgcn_s_barrier();
    }

    // ---- epilogue
    #pragma unroll
    for (int mi = 0; mi < 8; mi++) {
        const int row = m0 + wm * 128 + mi * 16 + quad * 4;
        #pragma unroll
        for (int n = 0; n < 4; n++) {
            const int col = n0 + wn * 64 + n * 16 + l16;
            float bval = 0.f;
            if (BIAS) bval = bias[col];
            #pragma unroll
            for (int r = 0; r < 4; r++) {
                float v = acc[mi][n][r];
                if (ELU) { if (col < 2 * NC) v = (v > 0.f) ? v + 1.f : __expf(v); }
                if (BIAS) v += bval;
                if (sizeof(OutT) == 2) Cout[(size_t)(row + r) * LDC + col] = (OutT)f2bf(v);
                else                   Cout[(size_t)(row + r) * LDC + col] = (OutT)v;
            }
        }
    }
}

// ============ 128x128 2-phase GEMM (proj): better tail at small N ============
// 256 threads (4 waves, 2x2), 4x4 16x16x32 MFMA per wave, BK=32, 16 KiB LDS
// -> 2 blocks/CU; grid 6x256 = 1536 blocks = 3 exact generations.
template<int LDC, bool ELU, bool BIAS, typename OutT>
__global__ __launch_bounds__(256) void gemm_bt(const ushort* __restrict__ A,
                                               const ushort* __restrict__ Bw,
                                               const float* __restrict__ bias,
                                               OutT* __restrict__ Cout, int K) {
    __shared__ ushort As[128 * 32];
    __shared__ ushort Bs[128 * 32];
    const int t = threadIdx.x;
    const int w = t >> 6, lane = t & 63, l16 = lane & 15, quad = lane >> 4;
    const int wm = w & 1, wn = w >> 1;
    const int m0 = blockIdx.y * 128, n0 = blockIdx.x * 128;

    floatx4 acc[4][4] = {};

    const int rowA = t >> 2, chA = t & 3;            // 64 rows x 4 chunks of 16B
    const ushort* gA = A  + (size_t)(m0 + rowA) * K + chA * 8;
    const ushort* gB = Bw + (size_t)(n0 + rowA) * K + chA * 8;

    for (int k0 = 0; k0 < K; k0 += 32) {
        gl_lds16(gA + k0,                As + w * 512);
        gl_lds16(gA + k0 + 64 * K,       As + 2048 + w * 512);
        gl_lds16(gB + k0,                Bs + w * 512);
        gl_lds16(gB + k0 + 64 * K,       Bs + 2048 + w * 512);
        __syncthreads();
        short8 af[4], bfr[4];
        #pragma unroll
        for (int i = 0; i < 4; i++)
            af[i] = *(const short8*)&As[(wm * 64 + i * 16 + l16) * 32 + quad * 8];
        #pragma unroll
        for (int j = 0; j < 4; j++)
            bfr[j] = *(const short8*)&Bs[(wn * 64 + j * 16 + l16) * 32 + quad * 8];
        #pragma unroll
        for (int i = 0; i < 4; i++)
            #pragma unroll
            for (int j = 0; j < 4; j++)
                acc[i][j] = __builtin_amdgcn_mfma_f32_16x16x32_bf16(af[i], bfr[j], acc[i][j], 0, 0, 0);
        __syncthreads();
    }

    #pragma unroll
    for (int i = 0; i < 4; i++) {
        const int row = m0 + wm * 64 + i * 16 + quad * 4;
        #pragma unroll
        for (int j = 0; j < 4; j++) {
            const int col = n0 + wn * 64 + j * 16 + l16;
            float bval = 0.f;
            if (BIAS) bval = bias[col];
            #pragma unroll
            for (int r = 0; r < 4; r++) {
                float v = acc[i][j][r];
                if (ELU) { if (col < 2 * NC) v = (v > 0.f) ? v + 1.f : __expf(v); }
                if (BIAS) v += bval;
                if (sizeof(OutT) == 2) Cout[(size_t)(row + r) * LDC + col] = (OutT)f2bf(v);
                else                   Cout[(size_t)(row + r) * LDC + col] = (OutT)v;
            }
        }
    }
}

// ---------- kv_part[c][bh][d][e] = sum_n k[n,d] v[n,e] over n-chunk c; also ksum ----------
// atomics-free; ksum via MFMA vs all-ones. Counted-vmcnt double-buffered staging
// (R4-measured: −21 us vs syncthreads). Grid 8x48; 1024 rows = 8 stages of 128.
__global__ __launch_bounds__(256) void kv_ksum(const ushort* __restrict__ qkv,
                                               float* __restrict__ kv_part,
                                               float* __restrict__ ks_part) {
    __shared__ ushort kvsh[2][2][128 * 64];   // [buf][k/v][...]; reused as f32 scratch
    __shared__ float  ksred[4][64];
    const int bh = blockIdx.y, b = bh / NH, h = bh % NH;
    const int t = threadIdx.x, w = t >> 6, lane = t & 63, l16 = lane & 15, quad = lane >> 4;
    const int n0 = blockIdx.x * (NN / NCH);   // 1024 rows per chunk
    const ushort* kbase = qkv + (size_t)(b * NN) * LDQKV + NC     + h * ND;
    const ushort* vbase = qkv + (size_t)(b * NN) * LDQKV + 2 * NC + h * ND;

    floatx4 acc[4][4] = {};
    floatx4 aks[4] = {};
    short8 bones;
    #pragma unroll
    for (int j = 0; j < 8; j++) bones[j] = (short)0x3F80;   // bf16 1.0
    const int rowT = t >> 3, ch = t & 7;   // 32 rows x 8 chunks of 16B per issue

    // stage chunk s into buffer s&1 (8 gl_lds/thread)
    #define KV_STAGE(s) do {                                                  \
        const int nb_ = n0 + (s) * 128;                                       \
        _Pragma("unroll")                                                     \
        for (int i_ = 0; i_ < 4; i_++) {                                      \
            const size_t r_ = (size_t)(nb_ + i_ * 32 + rowT) * LDQKV + ch * 8;\
            gl_lds16(kbase + r_, &kvsh[(s) & 1][0][0] + i_ * 2048 + w * 512); \
            gl_lds16(vbase + r_, &kvsh[(s) & 1][1][0] + i_ * 2048 + w * 512); \
        }                                                                     \
    } while (0)

    KV_STAGE(0);
    for (int s = 0; s < 8; s++) {
        if (s < 7) KV_STAGE(s + 1);
        if (s < 7) asm volatile("s_waitcnt vmcnt(8)" ::: "memory");
        else       asm volatile("s_waitcnt vmcnt(0)" ::: "memory");
        __builtin_amdgcn_s_barrier();
        const ushort* klds = &kvsh[s & 1][0][0];
        const ushort* vlds = &kvsh[s & 1][1][0];
        short8 af[4], bfr[4];
        #pragma unroll
        for (int dt = 0; dt < 4; dt++) {
            short8 v;
            #pragma unroll
            for (int j = 0; j < 8; j++)
                v[j] = (short)klds[(w * 32 + quad * 8 + j) * 64 + dt * 16 + l16];
            af[dt] = v;
        }
        #pragma unroll
        for (int et = 0; et < 4; et++) {
            short8 v;
            #pragma unroll
            for (int j = 0; j < 8; j++)
                v[j] = (short)vlds[(w * 32 + quad * 8 + j) * 64 + et * 16 + l16];
            bfr[et] = v;
        }
        #pragma unroll
        for (int dt = 0; dt < 4; dt++) {
            #pragma unroll
            for (int et = 0; et < 4; et++)
                acc[dt][et] = __builtin_amdgcn_mfma_f32_16x16x32_bf16(af[dt], bfr[et], acc[dt][et], 0, 0, 0);
            aks[dt] = __builtin_amdgcn_mfma_f32_16x16x32_bf16(af[dt], bones, aks[dt], 0, 0, 0);
        }
        __builtin_amdgcn_s_barrier();   // buf s&1 reads done before stage(s+2) next iter
    }
    #undef KV_STAGE

    // ksum wave partials: lane l16==0 holds ksum[dt*16+quad*4+r] (dup over cols)
    if (l16 == 0) {
        #pragma unroll
        for (int dt = 0; dt < 4; dt++)
            #pragma unroll
            for (int r = 0; r < 4; r++)
                ksred[w][dt * 16 + quad * 4 + r] = aks[dt][r];
    }

    // kv barrier-tree reduce across the 4 waves via LDS scratch (no atomics)
    float* scratch = (float*)kvsh;         // 8192 floats needed, 64 KB available
    if (w >= 2) {
        float* dst = scratch + (w - 2) * 4096;
        #pragma unroll
        for (int dt = 0; dt < 4; dt++)
            #pragma unroll
            for (int et = 0; et < 4; et++)
                #pragma unroll
                for (int r = 0; r < 4; r++)
                    dst[(dt * 16 + quad * 4 + r) * 64 + et * 16 + l16] = acc[dt][et][r];
    }
    __syncthreads();
    if (w < 2) {
        const float* srcp = scratch + w * 4096;
        #pragma unroll
        for (int dt = 0; dt < 4; dt++)
            #pragma unroll
            for (int et = 0; et < 4; et++)
                #pragma unroll
                for (int r = 0; r < 4; r++)
                    acc[dt][et][r] += srcp[(dt * 16 + quad * 4 + r) * 64 + et * 16 + l16];
    }
    __syncthreads();
    if (w == 1) {
        #pragma unroll
        for (int dt = 0; dt < 4; dt++)
            #pragma unroll
            for (int et = 0; et < 4; et++)
                #pragma unroll
                for (int r = 0; r < 4; r++)
                    scratch[(dt * 16 + quad * 4 + r) * 64 + et * 16 + l16] = acc[dt][et][r];
    }
    __syncthreads();
    if (w == 0) {
        float* outp = kv_part + ((size_t)blockIdx.x * 48 + bh) * 4096;
        #pragma unroll
        for (int dt = 0; dt < 4; dt++)
            #pragma unroll
            for (int et = 0; et < 4; et++)
                #pragma unroll
                for (int r = 0; r < 4; r++) {
                    const int idx = (dt * 16 + quad * 4 + r) * 64 + et * 16 + l16;
                    outp[idx] = acc[dt][et][r] + scratch[idx];
                }
    }
    if (t < 64) ks_part[(size_t)blockIdx.x * 48 * 64 + bh * 64 + t] =
        ksred[0][t] + ksred[1][t] + ksred[2][t] + ksred[3][t];
}

// ---------- out_pre[b,n,h*64+e] = (q[n,:] @ kv) / (q[n,:]·ksum + 1e-6), bf16 ----------
// Grid 8x48; 1024 rows/block.
__global__ __launch_bounds__(256) void attn_apply(const ushort* __restrict__ qkv,
                                                  const float* __restrict__ kv_part,
                                                  const float* __restrict__ ks_part,
                                                  ushort* __restrict__ outpre) {
    __shared__ ushort kvb[64 * 80];
    const int bh = blockIdx.y, b = bh / NH, h = bh % NH;
    const int t = threadIdx.x, w = t >> 6, lane = t & 63, l16 = lane & 15, quad = lane >> 4;

    for (int i = t; i < 4096; i += 256) {
        float s = 0.f;
        #pragma unroll
        for (int c = 0; c < NCH; c++) s += kv_part[((size_t)c * 48 + bh) * 4096 + i];
        kvb[(i >> 6) * 80 + (i & 63)] = f2bf(s);
    }
    for (int i = t; i < 1024; i += 256) {
        const int d = i >> 4, c = i & 15;
        float s = 0.f;
        if (c == 0) {
            #pragma unroll
            for (int cc = 0; cc < NCH; cc++) s += ks_part[(size_t)cc * 48 * 64 + bh * 64 + d];
        }
        kvb[d * 80 + 64 + c] = (c == 0) ? f2bf(s) : (ushort)0;
    }
    __syncthreads();

    short8 bfr[5][2];
    #pragma unroll
    for (int et = 0; et < 5; et++)
        #pragma unroll
        for (int ks = 0; ks < 2; ks++) {
            short8 v;
            #pragma unroll
            for (int j = 0; j < 8; j++)
                v[j] = (short)kvb[(ks * 32 + quad * 8 + j) * 80 + et * 16 + l16];
            bfr[et][ks] = v;
        }

    const ushort* qbase = qkv + (size_t)(b * NN) * LDQKV + h * ND;
    ushort* obase = outpre + (size_t)(b * NN) * NC + h * ND;
    const int n0 = blockIdx.x * (NN / NCH);   // 1024 rows/block

    for (int it = 0; it < 16; it++) {
        const int nt = n0 + (it * 4 + w) * 16;
        const ushort* qp = qbase + (size_t)(nt + l16) * LDQKV + quad * 8;
        const short8 a0 = *(const short8*)qp;
        const short8 a1 = *(const short8*)(qp + 32);
        floatx4 acc[5] = {};
        #pragma unroll
        for (int et = 0; et < 5; et++) {
            acc[et] = __builtin_amdgcn_mfma_f32_16x16x32_bf16(a0, bfr[et][0], acc[et], 0, 0, 0);
            acc[et] = __builtin_amdgcn_mfma_f32_16x16x32_bf16(a1, bfr[et][1], acc[et], 0, 0, 0);
        }
        float dv[4];
        #pragma unroll
        for (int r = 0; r < 4; r++) dv[r] = __shfl(acc[4][r], lane & 48);
        #pragma unroll
        for (int et = 0; et < 4; et++)
            #pragma unroll
            for (int r = 0; r < 4; r++) {
                const float o = acc[et][r] / (dv[r] + 1e-6f);
                obase[(size_t)(nt + quad * 4 + r) * NC + et * 16 + l16] = f2bf(o);
            }
    }
}

extern "C" void kernel_launch(void* const* d_in, const int* in_sizes, int n_in,
                              void* d_out, int out_size, void* d_ws, size_t ws_size,
                              hipStream_t stream) {
    (void)in_sizes; (void)n_in; (void)out_size; (void)ws_size;
    const float* X     = (const float*)d_in[0];   // [4,8192,768] fp32
    const float* Wqkv  = (const float*)d_in[1];   // [2304,768]   fp32
    const float* Wproj = (const float*)d_in[2];   // [768,768]    fp32
    const float* bproj = (const float*)d_in[3];   // [768]        fp32
    float* out = (float*)d_out;                   // [4,8192,768] fp32

    char* ws = (char*)d_ws;
    size_t off = 0;
    ushort* qkv     = (ushort*)(ws + off); off += (size_t)32768 * 2304 * 2;  // 150,994,944
    ushort* outpre  = (ushort*)(ws + off); off += (size_t)32768 * 768 * 2;   //  50,331,648
    ushort* xbf     = (ushort*)(ws + off); off += (size_t)32768 * 768 * 2;   //  50,331,648
    ushort* wqkvbf  = (ushort*)(ws + off); off += (size_t)2304 * 768 * 2;    //   3,538,944
    ushort* wprojbf = (ushort*)(ws + off);                                    //   1,179,648
    // kv/ks partials alias xbf's space: xbf is dead once the QKV GEMM finishes,
    // kv_ksum runs strictly after it (stream order).  6.34 MB << 50 MB.
    float* kv_part = (float*)xbf;                          // [8][48][4096] f32
    float* ks_part = kv_part + (size_t)NCH * 48 * 4096;    // [8][48][64]   f32

    // fp32->bf16 conversions, one launch for all three tensors
    cvt_bf16_3<<<CVT_NB0 + CVT_NB1 + CVT_NB2, 256, 0, stream>>>(
        X, xbf, Wqkv, wqkvbf, Wproj, wprojbf);

    // QKV: M=32768, N=2304 -> grid 9 x 128 = 1152 wgs (%8==0 for XCD swizzle)
    gemm256<LDQKV, true, false, ushort><<<dim3(9, 128), 512, 0, stream>>>(xbf, wqkvbf, nullptr, qkv, NC);
    kv_ksum<<<dim3(NCH, 48), 256, 0, stream>>>(qkv, kv_part, ks_part);
    attn_apply<<<dim3(NCH, 48), 256, 0, stream>>>(qkv, kv_part, ks_part, outpre);
    // proj: M=32768, N=768 -> grid 6 x 256 = 1536 blocks, 2/CU -> 3 exact gens
    gemm_bt<NC, false, true, float><<<dim3(6, 256), 256, 0, stream>>>(outpre, wprojbf, bproj, out, NC);
}

// Round 9
// 439.105 us; speedup vs baseline: 1.0302x; 1.0035x over previous
//
#include <hip/hip_runtime.h>
#include <hip/hip_bf16.h>
#include <stdint.h>

typedef __attribute__((ext_vector_type(8))) short short8;
typedef __attribute__((ext_vector_type(4))) float floatx4;

#define NB 4
#define NN 8192
#define NC 768
#define NH 12
#define ND 64
#define LDQKV 2304
#define NCH 8    // n-chunks for kv_ksum / attn_apply (R4-measured optimum; NCH=16 cost +26us)

// ---------- helpers ----------
__device__ __forceinline__ float bf2f(ushort u) {
    union { float f; uint32_t i; } x; x.i = ((uint32_t)u) << 16; return x.f;
}
__device__ __forceinline__ ushort f2bf(float f) {
    union { float f; uint32_t i; } x; x.f = f;
    uint32_t r = x.i + 0x7fff + ((x.i >> 16) & 1);
    return (ushort)(r >> 16);
}
// async global->LDS, 16B per lane: lane i lands at ldsbase + 16*i (wave-uniform base).
typedef const __attribute__((address_space(1))) uint32_t* gas1_t;
typedef __attribute__((address_space(3))) uint32_t* las3_t;
__device__ __forceinline__ void gl_lds16(const void* g, const void* l) {
    __builtin_amdgcn_global_load_lds((gas1_t)(uintptr_t)g,
                                     (las3_t)(uint32_t)(uintptr_t)l, 16, 0, 0);
}

// ---------- fp32 -> bf16 bulk convert, 3 segments in one launch ----------
__device__ __forceinline__ void cvt8(const float* __restrict__ src,
                                     ushort* __restrict__ dst, int i) {
    const float4 a = *(const float4*)(src + i);
    const float4 b = *(const float4*)(src + i + 4);
    short8 v;
    v[0] = (short)f2bf(a.x); v[1] = (short)f2bf(a.y);
    v[2] = (short)f2bf(a.z); v[3] = (short)f2bf(a.w);
    v[4] = (short)f2bf(b.x); v[5] = (short)f2bf(b.y);
    v[6] = (short)f2bf(b.z); v[7] = (short)f2bf(b.w);
    *(short8*)(dst + i) = v;
}
// segment block counts (2048 elems per block)
#define CVT_NB0 (32768 * 768 / 2048)   // X    : 12288
#define CVT_NB1 (2304 * 768 / 2048)    // Wqkv :   864
#define CVT_NB2 (768 * 768 / 2048)     // Wproj:   288
__global__ __launch_bounds__(256) void cvt_bf16_3(const float* __restrict__ s0, ushort* __restrict__ d0,
                                                  const float* __restrict__ s1, ushort* __restrict__ d1,
                                                  const float* __restrict__ s2, ushort* __restrict__ d2) {
    int blk = blockIdx.x;
    if (blk < CVT_NB0) { cvt8(s0, d0, (blk * 256 + threadIdx.x) * 8); return; }
    blk -= CVT_NB0;
    if (blk < CVT_NB1) { cvt8(s1, d1, (blk * 256 + threadIdx.x) * 8); return; }
    blk -= CVT_NB1;
    cvt8(s2, d2, (blk * 256 + threadIdx.x) * 8);
}

// ============ 256x256 8-phase GEMM (QKV): C = act(A @ Bw^T) ============
// FROZEN schedule (R1/R3, measured 156 us): two-barrier phase lockstep,
// stages spread 2-2-2-2 across phases, lead-1 A / lead-2 B, vmcnt(4) at ph3.
// R2 (hoisted reads) and R4 (lead-2 everything) both regressed — do not deviate.
// R8 note: identical source measured 182us on a different container (chip-speed
// variance suspect) — this kernel doubles as the environment gauge.

// stage one 128x64 half-tile (2 x gl_lds16 per thread), source-side swizzle
__device__ __forceinline__ void stage_half(const ushort* __restrict__ src, int row0,
                                           int k0, int K, ushort* dst, int t, int w) {
    const int rsub = t >> 3;                       // 0..63
    const int ch = (t & 7) ^ (rsub & 7);           // inverse of read-side XOR
    const ushort* g0 = src + (size_t)(row0 + rsub) * K + k0 + ch * 8;
    gl_lds16(g0,                 dst + w * 512);
    gl_lds16(g0 + (size_t)64 * K, dst + 4096 + w * 512);
}

#define PHASE_SYNC() do {                                        \
    __builtin_amdgcn_s_barrier();                                \
    asm volatile("s_waitcnt lgkmcnt(0)" ::: "memory");           \
    __builtin_amdgcn_sched_barrier(0);                           \
} while (0)

template<int LDC, bool ELU, bool BIAS, typename OutT>
__global__ __launch_bounds__(512) void gemm256(const ushort* __restrict__ A,
                                               const ushort* __restrict__ Bw,
                                               const float* __restrict__ bias,
                                               OutT* __restrict__ Cout, int K) {
    __shared__ __align__(16) ushort SL[2][4][8192];   // [buf][region][128*64]
    const int t = threadIdx.x, w = t >> 6, lane = t & 63;
    const int l16 = lane & 15, quad = lane >> 4;
    const int wm = w >> 2, wn = w & 3;
    const int bro = (wn & 1) * 64;                    // row offset inside B region

    const int gx = gridDim.x;
    const int nwg = gx * gridDim.y;
    int bid = blockIdx.y * gx + blockIdx.x;
    bid = (bid & 7) * (nwg >> 3) + (bid >> 3);        // XCD swizzle (nwg % 8 == 0)
    const int m0 = (bid / gx) * 256;
    const int n0 = (bid % gx) * 256;
    const int NT = K >> 6;                            // K-tiles of 64 (NT >= 3)

    floatx4 acc[8][4] = {};
    short8 af[4][2], b01[2][2], b23[2][2];

    // prologue: K0 {B0,B1,A0,A1}, K1 {B0,B1}  -> 12 loads/thread
    stage_half(Bw, n0,       0,  K, &SL[0][0][0], t, w);
    stage_half(Bw, n0 + 128, 0,  K, &SL[0][1][0], t, w);
    stage_half(A,  m0,       0,  K, &SL[0][2][0], t, w);
    stage_half(A,  m0 + 128, 0,  K, &SL[0][3][0], t, w);
    stage_half(Bw, n0,       64, K, &SL[1][0][0], t, w);
    stage_half(Bw, n0 + 128, 64, K, &SL[1][1][0], t, w);
    asm volatile("s_waitcnt vmcnt(4)" ::: "memory");  // K0 fully resident
    __builtin_amdgcn_s_barrier();

    for (int j = 0; j < NT; j++) {
        const int buf = j & 1;
        const ushort* As = &SL[buf][2 + wm][0];
        const ushort* Bs = &SL[buf][wn >> 1][0];

        // ---- phase 0: read A(m_lo) + B(n0,n1) [12 ds_reads]; stage A-lo(j+1)
        #pragma unroll
        for (int mi = 0; mi < 4; mi++) {
            const int row = mi * 16 + l16;
            const int sw = (row & 7) << 3;
            const int base = row * 64 + quad * 8;
            af[mi][0] = *(const short8*)&As[base ^ sw];
            af[mi][1] = *(const short8*)&As[(base + 32) ^ sw];
        }
        #pragma unroll
        for (int ni = 0; ni < 2; ni++) {
            const int row = bro + ni * 16 + l16;
            const int sw = (row & 7) << 3;
            const int base = row * 64 + quad * 8;
            b01[ni][0] = *(const short8*)&Bs[base ^ sw];
            b01[ni][1] = *(const short8*)&Bs[(base + 32) ^ sw];
        }
        if (j + 1 < NT) stage_half(A, m0, (j + 1) * 64, K, &SL[buf ^ 1][2][0], t, w);
        asm volatile("s_waitcnt lgkmcnt(8)" ::: "memory");  // template hint: 12 reads issued
        PHASE_SYNC();
        __builtin_amdgcn_s_setprio(1);
        #pragma unroll
        for (int mi = 0; mi < 4; mi++)
            #pragma unroll
            for (int ni = 0; ni < 2; ni++) {
                acc[mi][ni] = __builtin_amdgcn_mfma_f32_16x16x32_bf16(af[mi][0], b01[ni][0], acc[mi][ni], 0, 0, 0);
                acc[mi][ni] = __builtin_amdgcn_mfma_f32_16x16x32_bf16(af[mi][1], b01[ni][1], acc[mi][ni], 0, 0, 0);
            }
        __builtin_amdgcn_s_setprio(0);
        __builtin_amdgcn_s_barrier();

        // ---- phase 1: read B(n2,n3); stage A-hi(j+1); MFMA m_lo x n23
        #pragma unroll
        for (int ni = 0; ni < 2; ni++) {
            const int row = bro + (2 + ni) * 16 + l16;
            const int sw = (row & 7) << 3;
            const int base = row * 64 + quad * 8;
            b23[ni][0] = *(const short8*)&Bs[base ^ sw];
            b23[ni][1] = *(const short8*)&Bs[(base + 32) ^ sw];
        }
        if (j + 1 < NT) stage_half(A, m0 + 128, (j + 1) * 64, K, &SL[buf ^ 1][3][0], t, w);
        PHASE_SYNC();
        __builtin_amdgcn_s_setprio(1);
        #pragma unroll
        for (int mi = 0; mi < 4; mi++)
            #pragma unroll
            for (int ni = 0; ni < 2; ni++) {
                acc[mi][2 + ni] = __builtin_amdgcn_mfma_f32_16x16x32_bf16(af[mi][0], b23[ni][0], acc[mi][2 + ni], 0, 0, 0);
                acc[mi][2 + ni] = __builtin_amdgcn_mfma_f32_16x16x32_bf16(af[mi][1], b23[ni][1], acc[mi][2 + ni], 0, 0, 0);
            }
        __builtin_amdgcn_s_setprio(0);
        __builtin_amdgcn_s_barrier();

        // ---- phase 2: read A(m_hi); stage B-lo(j+2); MFMA m_hi x n01
        #pragma unroll
        for (int mi = 0; mi < 4; mi++) {
            const int row = (4 + mi) * 16 + l16;
            const int sw = (row & 7) << 3;
            const int base = row * 64 + quad * 8;
            af[mi][0] = *(const short8*)&As[base ^ sw];
            af[mi][1] = *(const short8*)&As[(base + 32) ^ sw];
        }
        if (j + 2 < NT) stage_half(Bw, n0, (j + 2) * 64, K, &SL[buf][0][0], t, w);
        PHASE_SYNC();
        __builtin_amdgcn_s_setprio(1);
        #pragma unroll
        for (int mi = 0; mi < 4; mi++)
            #pragma unroll
            for (int ni = 0; ni < 2; ni++) {
                acc[4 + mi][ni] = __builtin_amdgcn_mfma_f32_16x16x32_bf16(af[mi][0], b01[ni][0], acc[4 + mi][ni], 0, 0, 0);
                acc[4 + mi][ni] = __builtin_amdgcn_mfma_f32_16x16x32_bf16(af[mi][1], b01[ni][1], acc[4 + mi][ni], 0, 0, 0);
            }
        __builtin_amdgcn_s_setprio(0);
        __builtin_amdgcn_s_barrier();

        // ---- phase 3: stage B-hi(j+2); MFMA m_hi x n23; boundary vmcnt
        if (j + 2 < NT) stage_half(Bw, n0 + 128, (j + 2) * 64, K, &SL[buf][1][0], t, w);
        __builtin_amdgcn_s_barrier();
        __builtin_amdgcn_s_setprio(1);
        #pragma unroll
        for (int mi = 0; mi < 4; mi++)
            #pragma unroll
            for (int ni = 0; ni < 2; ni++) {
                acc[4 + mi][2 + ni] = __builtin_amdgcn_mfma_f32_16x16x32_bf16(af[mi][0], b23[ni][0], acc[4 + mi][2 + ni], 0, 0, 0);
                acc[4 + mi][2 + ni] = __builtin_amdgcn_mfma_f32_16x16x32_bf16(af[mi][1], b23[ni][1], acc[4 + mi][2 + ni], 0, 0, 0);
            }
        __builtin_amdgcn_s_setprio(0);
        // tile j+1 must be resident after this barrier; leave B(j+2) in flight
        if (j < NT - 2) asm volatile("s_waitcnt vmcnt(4)" ::: "memory");
        else            asm volatile("s_waitcnt vmcnt(0)" ::: "memory");
        __builtin_amdgcn_s_barrier();
    }

    // ---- epilogue
    #pragma unroll
    for (int mi = 0; mi < 8; mi++) {
        const int row = m0 + wm * 128 + mi * 16 + quad * 4;
        #pragma unroll
        for (int n = 0; n < 4; n++) {
            const int col = n0 + wn * 64 + n * 16 + l16;
            float bval = 0.f;
            if (BIAS) bval = bias[col];
            #pragma unroll
            for (int r = 0; r < 4; r++) {
                float v = acc[mi][n][r];
                if (ELU) { if (col < 2 * NC) v = (v > 0.f) ? v + 1.f : __expf(v); }
                if (BIAS) v += bval;
                if (sizeof(OutT) == 2) Cout[(size_t)(row + r) * LDC + col] = (OutT)f2bf(v);
                else                   Cout[(size_t)(row + r) * LDC + col] = (OutT)v;
            }
        }
    }
}

// ============ 128x128 2-phase GEMM (proj) ============
// v2: double-buffered LDS + raw s_barrier + counted vmcnt(4) — same fix that
// measured −21us on kv_ksum (R4). Old __syncthreads drained vmcnt(0) every
// K-iter -> 24 exposed round-trips. LDS 32 KiB -> still 2 blocks/CU.
// vmcnt ledger: stage(s+1)=4 loads; vmcnt(4) retires exactly buf(s)'s 4;
// buf restage happens one compute+barrier after its last ds_read (race-free).
template<int LDC, bool ELU, bool BIAS, typename OutT>
__global__ __launch_bounds__(256) void gemm_bt(const ushort* __restrict__ A,
                                               const ushort* __restrict__ Bw,
                                               const float* __restrict__ bias,
                                               OutT* __restrict__ Cout, int K) {
    __shared__ ushort As[2][128 * 32];
    __shared__ ushort Bs[2][128 * 32];
    const int t = threadIdx.x;
    const int w = t >> 6, lane = t & 63, l16 = lane & 15, quad = lane >> 4;
    const int wm = w & 1, wn = w >> 1;
    const int m0 = blockIdx.y * 128, n0 = blockIdx.x * 128;

    floatx4 acc[4][4] = {};

    const int rowA = t >> 2, chA = t & 3;            // 64 rows x 4 chunks of 16B
    const ushort* gA = A  + (size_t)(m0 + rowA) * K + chA * 8;
    const ushort* gB = Bw + (size_t)(n0 + rowA) * K + chA * 8;
    const int NT = K >> 5;                            // K-steps of 32

    #define PJ_STAGE(s) do {                                       \
        const int k0_ = (s) * 32;                                  \
        ushort* as_ = &As[(s) & 1][0];                             \
        ushort* bs_ = &Bs[(s) & 1][0];                             \
        gl_lds16(gA + k0_,            as_ + w * 512);              \
        gl_lds16(gA + k0_ + 64 * K,   as_ + 2048 + w * 512);       \
        gl_lds16(gB + k0_,            bs_ + w * 512);              \
        gl_lds16(gB + k0_ + 64 * K,   bs_ + 2048 + w * 512);       \
    } while (0)

    PJ_STAGE(0);
    for (int s = 0; s < NT; s++) {
        if (s + 1 < NT) PJ_STAGE(s + 1);
        if (s + 1 < NT) asm volatile("s_waitcnt vmcnt(4)" ::: "memory");
        else            asm volatile("s_waitcnt vmcnt(0)" ::: "memory");
        __builtin_amdgcn_s_barrier();
        const ushort* as_ = &As[s & 1][0];
        const ushort* bs_ = &Bs[s & 1][0];
        short8 af[4], bfr[4];
        #pragma unroll
        for (int i = 0; i < 4; i++)
            af[i] = *(const short8*)&as_[(wm * 64 + i * 16 + l16) * 32 + quad * 8];
        #pragma unroll
        for (int j = 0; j < 4; j++)
            bfr[j] = *(const short8*)&bs_[(wn * 64 + j * 16 + l16) * 32 + quad * 8];
        #pragma unroll
        for (int i = 0; i < 4; i++)
            #pragma unroll
            for (int j = 0; j < 4; j++)
                acc[i][j] = __builtin_amdgcn_mfma_f32_16x16x32_bf16(af[i], bfr[j], acc[i][j], 0, 0, 0);
        __builtin_amdgcn_s_barrier();   // reads of buf s&1 done before restage next iter
    }
    #undef PJ_STAGE

    #pragma unroll
    for (int i = 0; i < 4; i++) {
        const int row = m0 + wm * 64 + i * 16 + quad * 4;
        #pragma unroll
        for (int j = 0; j < 4; j++) {
            const int col = n0 + wn * 64 + j * 16 + l16;
            float bval = 0.f;
            if (BIAS) bval = bias[col];
            #pragma unroll
            for (int r = 0; r < 4; r++) {
                float v = acc[i][j][r];
                if (ELU) { if (col < 2 * NC) v = (v > 0.f) ? v + 1.f : __expf(v); }
                if (BIAS) v += bval;
                if (sizeof(OutT) == 2) Cout[(size_t)(row + r) * LDC + col] = (OutT)f2bf(v);
                else                   Cout[(size_t)(row + r) * LDC + col] = (OutT)v;
            }
        }
    }
}

// ---------- kv_part[c][bh][d][e] = sum_n k[n,d] v[n,e] over n-chunk c; also ksum ----------
// atomics-free; ksum via MFMA vs all-ones. Counted-vmcnt double-buffered staging
// (R4-measured: −21 us vs syncthreads). Grid 8x48; 1024 rows = 8 stages of 128.
__global__ __launch_bounds__(256) void kv_ksum(const ushort* __restrict__ qkv,
                                               float* __restrict__ kv_part,
                                               float* __restrict__ ks_part) {
    __shared__ ushort kvsh[2][2][128 * 64];   // [buf][k/v][...]; reused as f32 scratch
    __shared__ float  ksred[4][64];
    const int bh = blockIdx.y, b = bh / NH, h = bh % NH;
    const int t = threadIdx.x, w = t >> 6, lane = t & 63, l16 = lane & 15, quad = lane >> 4;
    const int n0 = blockIdx.x * (NN / NCH);   // 1024 rows per chunk
    const ushort* kbase = qkv + (size_t)(b * NN) * LDQKV + NC     + h * ND;
    const ushort* vbase = qkv + (size_t)(b * NN) * LDQKV + 2 * NC + h * ND;

    floatx4 acc[4][4] = {};
    floatx4 aks[4] = {};
    short8 bones;
    #pragma unroll
    for (int j = 0; j < 8; j++) bones[j] = (short)0x3F80;   // bf16 1.0
    const int rowT = t >> 3, ch = t & 7;   // 32 rows x 8 chunks of 16B per issue

    // stage chunk s into buffer s&1 (8 gl_lds/thread)
    #define KV_STAGE(s) do {                                                  \
        const int nb_ = n0 + (s) * 128;                                       \
        _Pragma("unroll")                                                     \
        for (int i_ = 0; i_ < 4; i_++) {                                      \
            const size_t r_ = (size_t)(nb_ + i_ * 32 + rowT) * LDQKV + ch * 8;\
            gl_lds16(kbase + r_, &kvsh[(s) & 1][0][0] + i_ * 2048 + w * 512); \
            gl_lds16(vbase + r_, &kvsh[(s) & 1][1][0] + i_ * 2048 + w * 512); \
        }                                                                     \
    } while (0)

    KV_STAGE(0);
    for (int s = 0; s < 8; s++) {
        if (s < 7) KV_STAGE(s + 1);
        if (s < 7) asm volatile("s_waitcnt vmcnt(8)" ::: "memory");
        else       asm volatile("s_waitcnt vmcnt(0)" ::: "memory");
        __builtin_amdgcn_s_barrier();
        const ushort* klds = &kvsh[s & 1][0][0];
        const ushort* vlds = &kvsh[s & 1][1][0];
        short8 af[4], bfr[4];
        #pragma unroll
        for (int dt = 0; dt < 4; dt++) {
            short8 v;
            #pragma unroll
            for (int j = 0; j < 8; j++)
                v[j] = (short)klds[(w * 32 + quad * 8 + j) * 64 + dt * 16 + l16];
            af[dt] = v;
        }
        #pragma unroll
        for (int et = 0; et < 4; et++) {
            short8 v;
            #pragma unroll
            for (int j = 0; j < 8; j++)
                v[j] = (short)vlds[(w * 32 + quad * 8 + j) * 64 + et * 16 + l16];
            bfr[et] = v;
        }
        #pragma unroll
        for (int dt = 0; dt < 4; dt++) {
            #pragma unroll
            for (int et = 0; et < 4; et++)
                acc[dt][et] = __builtin_amdgcn_mfma_f32_16x16x32_bf16(af[dt], bfr[et], acc[dt][et], 0, 0, 0);
            aks[dt] = __builtin_amdgcn_mfma_f32_16x16x32_bf16(af[dt], bones, aks[dt], 0, 0, 0);
        }
        __builtin_amdgcn_s_barrier();   // buf s&1 reads done before stage(s+2) next iter
    }
    #undef KV_STAGE

    // ksum wave partials: lane l16==0 holds ksum[dt*16+quad*4+r] (dup over cols)
    if (l16 == 0) {
        #pragma unroll
        for (int dt = 0; dt < 4; dt++)
            #pragma unroll
            for (int r = 0; r < 4; r++)
                ksred[w][dt * 16 + quad * 4 + r] = aks[dt][r];
    }

    // kv barrier-tree reduce across the 4 waves via LDS scratch (no atomics)
    float* scratch = (float*)kvsh;         // 8192 floats needed, 64 KB available
    if (w >= 2) {
        float* dst = scratch + (w - 2) * 4096;
        #pragma unroll
        for (int dt = 0; dt < 4; dt++)
            #pragma unroll
            for (int et = 0; et < 4; et++)
                #pragma unroll
                for (int r = 0; r < 4; r++)
                    dst[(dt * 16 + quad * 4 + r) * 64 + et * 16 + l16] = acc[dt][et][r];
    }
    __syncthreads();
    if (w < 2) {
        const float* srcp = scratch + w * 4096;
        #pragma unroll
        for (int dt = 0; dt < 4; dt++)
            #pragma unroll
            for (int et = 0; et < 4; et++)
                #pragma unroll
                for (int r = 0; r < 4; r++)
                    acc[dt][et][r] += srcp[(dt * 16 + quad * 4 + r) * 64 + et * 16 + l16];
    }
    __syncthreads();
    if (w == 1) {
        #pragma unroll
        for (int dt = 0; dt < 4; dt++)
            #pragma unroll
            for (int et = 0; et < 4; et++)
                #pragma unroll
                for (int r = 0; r < 4; r++)
                    scratch[(dt * 16 + quad * 4 + r) * 64 + et * 16 + l16] = acc[dt][et][r];
    }
    __syncthreads();
    if (w == 0) {
        float* outp = kv_part + ((size_t)blockIdx.x * 48 + bh) * 4096;
        #pragma unroll
        for (int dt = 0; dt < 4; dt++)
            #pragma unroll
            for (int et = 0; et < 4; et++)
                #pragma unroll
                for (int r = 0; r < 4; r++) {
                    const int idx = (dt * 16 + quad * 4 + r) * 64 + et * 16 + l16;
                    outp[idx] = acc[dt][et][r] + scratch[idx];
                }
    }
    if (t < 64) ks_part[(size_t)blockIdx.x * 48 * 64 + bh * 64 + t] =
        ksred[0][t] + ksred[1][t] + ksred[2][t] + ksred[3][t];
}

// ---------- out_pre[b,n,h*64+e] = (q[n,:] @ kv) / (q[n,:]·ksum + 1e-6), bf16 ----------
// Grid 8x48; 1024 rows/block.
__global__ __launch_bounds__(256) void attn_apply(const ushort* __restrict__ qkv,
                                                  const float* __restrict__ kv_part,
                                                  const float* __restrict__ ks_part,
                                                  ushort* __restrict__ outpre) {
    __shared__ ushort kvb[64 * 80];
    const int bh = blockIdx.y, b = bh / NH, h = bh % NH;
    const int t = threadIdx.x, w = t >> 6, lane = t & 63, l16 = lane & 15, quad = lane >> 4;

    for (int i = t; i < 4096; i += 256) {
        float s = 0.f;
        #pragma unroll
        for (int c = 0; c < NCH; c++) s += kv_part[((size_t)c * 48 + bh) * 4096 + i];
        kvb[(i >> 6) * 80 + (i & 63)] = f2bf(s);
    }
    for (int i = t; i < 1024; i += 256) {
        const int d = i >> 4, c = i & 15;
        float s = 0.f;
        if (c == 0) {
            #pragma unroll
            for (int cc = 0; cc < NCH; cc++) s += ks_part[(size_t)cc * 48 * 64 + bh * 64 + d];
        }
        kvb[d * 80 + 64 + c] = (c == 0) ? f2bf(s) : (ushort)0;
    }
    __syncthreads();

    short8 bfr[5][2];
    #pragma unroll
    for (int et = 0; et < 5; et++)
        #pragma unroll
        for (int ks = 0; ks < 2; ks++) {
            short8 v;
            #pragma unroll
            for (int j = 0; j < 8; j++)
                v[j] = (short)kvb[(ks * 32 + quad * 8 + j) * 80 + et * 16 + l16];
            bfr[et][ks] = v;
        }

    const ushort* qbase = qkv + (size_t)(b * NN) * LDQKV + h * ND;
    ushort* obase = outpre + (size_t)(b * NN) * NC + h * ND;
    const int n0 = blockIdx.x * (NN / NCH);   // 1024 rows/block

    for (int it = 0; it < 16; it++) {
        const int nt = n0 + (it * 4 + w) * 16;
        const ushort* qp = qbase + (size_t)(nt + l16) * LDQKV + quad * 8;
        const short8 a0 = *(const short8*)qp;
        const short8 a1 = *(const short8*)(qp + 32);
        floatx4 acc[5] = {};
        #pragma unroll
        for (int et = 0; et < 5; et++) {
            acc[et] = __builtin_amdgcn_mfma_f32_16x16x32_bf16(a0, bfr[et][0], acc[et], 0, 0, 0);
            acc[et] = __builtin_amdgcn_mfma_f32_16x16x32_bf16(a1, bfr[et][1], acc[et], 0, 0, 0);
        }
        float dv[4];
        #pragma unroll
        for (int r = 0; r < 4; r++) dv[r] = __shfl(acc[4][r], lane & 48);
        #pragma unroll
        for (int et = 0; et < 4; et++)
            #pragma unroll
            for (int r = 0; r < 4; r++) {
                const float o = acc[et][r] / (dv[r] + 1e-6f);
                obase[(size_t)(nt + quad * 4 + r) * NC + et * 16 + l16] = f2bf(o);
            }
    }
}

extern "C" void kernel_launch(void* const* d_in, const int* in_sizes, int n_in,
                              void* d_out, int out_size, void* d_ws, size_t ws_size,
                              hipStream_t stream) {
    (void)in_sizes; (void)n_in; (void)out_size; (void)ws_size;
    const float* X     = (const float*)d_in[0];   // [4,8192,768] fp32
    const float* Wqkv  = (const float*)d_in[1];   // [2304,768]   fp32
    const float* Wproj = (const float*)d_in[2];   // [768,768]    fp32
    const float* bproj = (const float*)d_in[3];   // [768]        fp32
    float* out = (float*)d_out;                   // [4,8192,768] fp32

    char* ws = (char*)d_ws;
    size_t off = 0;
    ushort* qkv     = (ushort*)(ws + off); off += (size_t)32768 * 2304 * 2;  // 150,994,944
    ushort* outpre  = (ushort*)(ws + off); off += (size_t)32768 * 768 * 2;   //  50,331,648
    ushort* xbf     = (ushort*)(ws + off); off += (size_t)32768 * 768 * 2;   //  50,331,648
    ushort* wqkvbf  = (ushort*)(ws + off); off += (size_t)2304 * 768 * 2;    //   3,538,944
    ushort* wprojbf = (ushort*)(ws + off);                                    //   1,179,648
    // kv/ks partials alias xbf's space: xbf is dead once the QKV GEMM finishes,
    // kv_ksum runs strictly after it (stream order).  6.34 MB << 50 MB.
    float* kv_part = (float*)xbf;                          // [8][48][4096] f32
    float* ks_part = kv_part + (size_t)NCH * 48 * 4096;    // [8][48][64]   f32

    // fp32->bf16 conversions, one launch for all three tensors
    cvt_bf16_3<<<CVT_NB0 + CVT_NB1 + CVT_NB2, 256, 0, stream>>>(
        X, xbf, Wqkv, wqkvbf, Wproj, wprojbf);

    // QKV: M=32768, N=2304 -> grid 9 x 128 = 1152 wgs (%8==0 for XCD swizzle)
    gemm256<LDQKV, true, false, ushort><<<dim3(9, 128), 512, 0, stream>>>(xbf, wqkvbf, nullptr, qkv, NC);
    kv_ksum<<<dim3(NCH, 48), 256, 0, stream>>>(qkv, kv_part, ks_part);
    attn_apply<<<dim3(NCH, 48), 256, 0, stream>>>(qkv, kv_part, ks_part, outpre);
    // proj: M=32768, N=768 -> grid 6 x 256 = 1536 blocks, 2/CU -> 3 exact gens
    gemm_bt<NC, false, true, float><<<dim3(6, 256), 256, 0, stream>>>(outpre, wprojbf, bproj, out, NC);
}